// Round 1
// baseline (3515.947 us; speedup 1.0000x reference)
//
#include <hip/hip_runtime.h>
#include <cmath>

// Accumulator slots (floats) at start of workspace
#define ACC_L1   0
#define ACC_MSE  1
#define ACC_ST0  2
#define ACC_ST1  3
#define ACC_SP0  4
#define ACC_SP1  5
#define ACC_HV   6
#define ACC_WV   7
#define ACC_EXP  8
#define ACC_SPAT 9
#define ACC_PERC 10
#define ACC_SSIM 16   // + scale*12 + (cs?6:0) + img   (img = b*3+c)

struct GW { float g[11]; };

__device__ __forceinline__ float waveSum(float v) {
#pragma unroll
  for (int o = 32; o > 0; o >>= 1) v += __shfl_down(v, o, 64);
  return v;
}

// 256-thread 1D block sum; every thread must call it; all threads get total.
__device__ __forceinline__ float blockSum256(float v) {
  __shared__ float red[4];
  const int tid = threadIdx.x;
  v = waveSum(v);
  __syncthreads();              // protect red[] from previous use
  if ((tid & 63) == 0) red[tid >> 6] = v;
  __syncthreads();
  return red[0] + red[1] + red[2] + red[3];
}

// ---------------- small loss terms ----------------

// smooth-L1, mse, per-image sums (color), illumination hv/wv. N = 2*3*224*224.
__global__ __launch_bounds__(256) void basic_stats(const float* __restrict__ yt,
                                                   const float* __restrict__ yp,
                                                   float* __restrict__ acc) {
  const int N = 2 * 3 * 224 * 224;
  const int idx = blockIdx.x * 256 + threadIdx.x;
  float l1 = 0.f, mse = 0.f, st0 = 0.f, st1 = 0.f, sp0 = 0.f, sp1 = 0.f, hv = 0.f, wv = 0.f;
  if (idx < N) {
    const float t = yt[idx], p = yp[idx];
    const float d = p - t;
    const float ad = fabsf(d);
    l1 = (ad < 1.f) ? 0.5f * d * d : ad - 0.5f;
    mse = d * d;
    const int b = idx / (3 * 224 * 224);
    if (b == 0) { st0 = t; sp0 = p; } else { st1 = t; sp1 = p; }
    const int w = idx % 224;
    const int h = (idx / 224) % 224;
    if (h < 223) { const float dv = yp[idx + 224] - p; hv = dv * dv; }
    if (w < 223) { const float dw = yp[idx + 1] - p; wv = dw * dw; }
  }
  float s;
  s = blockSum256(l1);  if (threadIdx.x == 0) atomicAdd(acc + ACC_L1, s);
  s = blockSum256(mse); if (threadIdx.x == 0) atomicAdd(acc + ACC_MSE, s);
  s = blockSum256(st0); if (threadIdx.x == 0) atomicAdd(acc + ACC_ST0, s);
  s = blockSum256(st1); if (threadIdx.x == 0) atomicAdd(acc + ACC_ST1, s);
  s = blockSum256(sp0); if (threadIdx.x == 0) atomicAdd(acc + ACC_SP0, s);
  s = blockSum256(sp1); if (threadIdx.x == 0) atomicAdd(acc + ACC_SP1, s);
  s = blockSum256(hv);  if (threadIdx.x == 0) atomicAdd(acc + ACC_HV, s);
  s = blockSum256(wv);  if (threadIdx.x == 0) atomicAdd(acc + ACC_WV, s);
}

// exposure: 16x16 avg pool of channel-mean of y_pred, (m-0.6)^2, 392 blocks
__global__ __launch_bounds__(256) void exposure_k(const float* __restrict__ yp,
                                                  float* __restrict__ acc) {
  const int blk = blockIdx.x;          // b*196 + py*14 + px
  const int b = blk / 196;
  const int rem = blk - b * 196;
  const int py = rem / 14, px = rem - py * 14;
  float s = 0.f;
  for (int e = threadIdx.x; e < 768; e += 256) {
    const int c = e >> 8;
    const int rr = (e >> 4) & 15;
    const int cc = e & 15;
    s += yp[(((size_t)b * 3 + c) * 224 + py * 16 + rr) * 224 + px * 16 + cc];
  }
  const float t = blockSum256(s);
  if (threadIdx.x == 0) {
    const float m = t * (1.f / 768.f) - 0.6f;
    atomicAdd(acc + ACC_EXP, m * m);
  }
}

// 4x4 avg pool of channel-mean -> op (y_true), ep (y_pred): (2,56,56)
__global__ __launch_bounds__(256) void pool4_lum_k(const float* __restrict__ yt,
                                                   const float* __restrict__ yp,
                                                   float* __restrict__ op,
                                                   float* __restrict__ ep) {
  const int idx = blockIdx.x * 256 + threadIdx.x;
  if (idx >= 2 * 56 * 56) return;
  const int b = idx / 3136;
  const int rem = idx - b * 3136;
  const int r = rem / 56, cl = rem - r * 56;
  float so = 0.f, se = 0.f;
  for (int c = 0; c < 3; ++c)
    for (int dy = 0; dy < 4; ++dy)
      for (int dx = 0; dx < 4; ++dx) {
        const size_t off = (((size_t)b * 3 + c) * 224 + (r * 4 + dy)) * 224 + cl * 4 + dx;
        so += yt[off]; se += yp[off];
      }
  op[idx] = so * (1.f / 48.f);
  ep[idx] = se * (1.f / 48.f);
}

// spatial consistency: 4 neighbor-difference kernels (SAME, zero pad), sum of sq diffs
__global__ __launch_bounds__(256) void spat_k(const float* __restrict__ op,
                                              const float* __restrict__ ep,
                                              float* __restrict__ acc) {
  const int idx = blockIdx.x * 256 + threadIdx.x;
  float v = 0.f;
  if (idx < 6272) {
    const int rem = idx % 3136;
    const int r = rem / 56, cl = rem - r * 56;
    const float oc = op[idx], ec = ep[idx];
    const float ol = (cl > 0)  ? op[idx - 1]  : 0.f;
    const float el = (cl > 0)  ? ep[idx - 1]  : 0.f;
    const float orr = (cl < 55) ? op[idx + 1]  : 0.f;
    const float er  = (cl < 55) ? ep[idx + 1]  : 0.f;
    const float ou = (r > 0)   ? op[idx - 56] : 0.f;
    const float eu = (r > 0)   ? ep[idx - 56] : 0.f;
    const float od = (r < 55)  ? op[idx + 56] : 0.f;
    const float ed = (r < 55)  ? ep[idx + 56] : 0.f;
    float d;
    d = (oc - ol) - (ec - el);   v += d * d;
    d = (oc - orr) - (ec - er);  v += d * d;
    d = (oc - ou) - (ec - eu);   v += d * d;
    d = (oc - od) - (ec - ed);   v += d * d;
  }
  const float t = blockSum256(v);
  if (threadIdx.x == 0) atomicAdd(acc + ACC_SPAT, t);
}

// ---------------- MS-SSIM ----------------

// vertical 11-tap gaussian of X, Y, XX, YY, XY. in: (6,n,n). out: 5 arrays (6,n-10,n)
__global__ __launch_bounds__(256) void gaussV_k(const float* __restrict__ X,
                                                const float* __restrict__ Y,
                                                float* __restrict__ tmp, int n, GW gw) {
  const int m = n - 10;
  const int total = 6 * m * n;
  const int idx = blockIdx.x * 256 + threadIdx.x;
  if (idx >= total) return;
  const int img = idx / (m * n);
  const int rem = idx - img * (m * n);
  const int r = rem / n, cl = rem - r * n;
  const float* xb = X + (size_t)img * n * n + (size_t)r * n + cl;
  const float* yb = Y + (size_t)img * n * n + (size_t)r * n + cl;
  float sx = 0.f, sy = 0.f, sxx = 0.f, syy = 0.f, sxy = 0.f;
#pragma unroll
  for (int t = 0; t < 11; ++t) {
    const float xv = xb[(size_t)t * n];
    const float yv = yb[(size_t)t * n];
    const float g = gw.g[t];
    sx += g * xv; sy += g * yv;
    sxx += g * xv * xv; syy += g * yv * yv; sxy += g * xv * yv;
  }
  const size_t st = (size_t)6 * m * n;
  tmp[idx] = sx; tmp[st + idx] = sy;
  tmp[2 * st + idx] = sxx; tmp[3 * st + idx] = syy; tmp[4 * st + idx] = sxy;
}

// horizontal 11-tap + per-pixel ssim/cs + per-(b,c) reduction
__global__ __launch_bounds__(256) void gaussH_ssim_k(const float* __restrict__ tmp,
                                                     float* __restrict__ acc,
                                                     int n, int scale, GW gw) {
  const int m = n - 10;
  const int img = blockIdx.y;
  const int pid = blockIdx.x * 256 + threadIdx.x;
  float sv = 0.f, cv = 0.f;
  if (pid < m * m) {
    const int r = pid / m, cl = pid - r * m;
    const size_t st = (size_t)6 * m * n;
    const float* t0 = tmp + (size_t)img * m * n + (size_t)r * n + cl;
    float mu1 = 0.f, mu2 = 0.f, e11 = 0.f, e22 = 0.f, e12 = 0.f;
#pragma unroll
    for (int t = 0; t < 11; ++t) {
      const float g = gw.g[t];
      mu1 += g * t0[t];
      mu2 += g * t0[st + t];
      e11 += g * t0[2 * st + t];
      e22 += g * t0[3 * st + t];
      e12 += g * t0[4 * st + t];
    }
    const float C1 = 1e-4f, C2 = 9e-4f;
    const float s11 = e11 - mu1 * mu1;
    const float s22 = e22 - mu2 * mu2;
    const float s12 = e12 - mu1 * mu2;
    cv = (2.f * s12 + C2) / (s11 + s22 + C2);
    sv = ((2.f * mu1 * mu2 + C1) / (mu1 * mu1 + mu2 * mu2 + C1)) * cv;
  }
  float t = blockSum256(sv);
  if (threadIdx.x == 0) atomicAdd(acc + ACC_SSIM + scale * 12 + img, t);
  t = blockSum256(cv);
  if (threadIdx.x == 0) atomicAdd(acc + ACC_SSIM + scale * 12 + 6 + img, t);
}

// 2x2 avg pool: (6,n,n) -> (6,n/2,n/2)
__global__ __launch_bounds__(256) void down2_k(const float* __restrict__ X,
                                               float* __restrict__ O, int n) {
  const int h = n >> 1;
  const int total = 6 * h * h;
  const int idx = blockIdx.x * 256 + threadIdx.x;
  if (idx >= total) return;
  const int img = idx / (h * h);
  const int rem = idx - img * (h * h);
  const int r = rem / h, cl = rem - r * h;
  const float* xb = X + (size_t)img * n * n + (size_t)(2 * r) * n + 2 * cl;
  O[idx] = 0.25f * (xb[0] + xb[1] + xb[n] + xb[n + 1]);
}

// ---------------- VGG ----------------

// direct 3x3 SAME conv + bias + relu, single batch image.
// in: (Cin,H,W)  wt: (Cout,Cin,3,3)  out: (Cout,H,W)
// block (8,8,4): 8x8 spatial tile, 4 waves x 4 couts = 16 couts/block
// grid (W/8, H/8, Cout/16)
__global__ __launch_bounds__(256) void conv3x3_relu(
    const float* __restrict__ in, const float* __restrict__ wt,
    const float* __restrict__ bias, float* __restrict__ out,
    int Cin, int H, int W, int Cout) {
  __shared__ float sIn[8][10][12];   // row stride 12 -> exact 2-way LDS bank aliasing (free)
  const int tx = threadIdx.x, ty = threadIdx.y, tz = threadIdx.z;
  const int tid = (tz << 6) | (ty << 3) | tx;
  const int x0 = blockIdx.x << 3, y0 = blockIdx.y << 3;
  const int x = x0 + tx, y = y0 + ty;
  const int co0 = blockIdx.z << 4;
  const int wstride = Cin * 9;
  // tz is the wave index (lanes 0..63 share tz) -> weight row is wave-uniform.
  int wrow = (co0 + (tz << 2)) * wstride;
  wrow = __builtin_amdgcn_readfirstlane(wrow);

  float acc0 = 0.f, acc1 = 0.f, acc2 = 0.f, acc3 = 0.f;

  for (int c0 = 0; c0 < Cin; c0 += 8) {
    int cb = Cin - c0; if (cb > 8) cb = 8;
    __syncthreads();
    for (int el = tid; el < cb * 100; el += 256) {
      const int ci = el / 100;
      const int rem = el - ci * 100;
      const int r = rem / 10;
      const int cl = rem - r * 10;
      const int gy = y0 - 1 + r, gx = x0 - 1 + cl;
      float v = 0.f;
      if (gy >= 0 && gy < H && gx >= 0 && gx < W)
        v = in[((size_t)(c0 + ci) * H + gy) * W + gx];
      sIn[ci][r][cl] = v;
    }
    __syncthreads();

    auto body = [&](int ci) {
      float xv[9];
#pragma unroll
      for (int ky = 0; ky < 3; ++ky)
#pragma unroll
        for (int kx = 0; kx < 3; ++kx)
          xv[ky * 3 + kx] = sIn[ci][ty + ky][tx + kx];
      const float* wp = wt + wrow + (size_t)(c0 + ci) * 9;
#pragma unroll
      for (int k = 0; k < 9; ++k) {
        acc0 = fmaf(xv[k], wp[k], acc0);
        acc1 = fmaf(xv[k], wp[wstride + k], acc1);
        acc2 = fmaf(xv[k], wp[2 * wstride + k], acc2);
        acc3 = fmaf(xv[k], wp[3 * wstride + k], acc3);
      }
    };
    if (cb == 8) {
#pragma unroll
      for (int ci = 0; ci < 8; ++ci) body(ci);
    } else {
      for (int ci = 0; ci < cb; ++ci) body(ci);
    }
  }

  const int coB = co0 + (tz << 2);
  out[((size_t)(coB + 0) * H + y) * W + x] = fmaxf(acc0 + bias[coB + 0], 0.f);
  out[((size_t)(coB + 1) * H + y) * W + x] = fmaxf(acc1 + bias[coB + 1], 0.f);
  out[((size_t)(coB + 2) * H + y) * W + x] = fmaxf(acc2 + bias[coB + 2], 0.f);
  out[((size_t)(coB + 3) * H + y) * W + x] = fmaxf(acc3 + bias[coB + 3], 0.f);
}

// 2x2 stride-2 VALID maxpool: (NC,H,W) -> (NC,H/2,W/2)
__global__ __launch_bounds__(256) void maxpool2_k(const float* __restrict__ in,
                                                  float* __restrict__ out,
                                                  int NC, int H, int W) {
  const int h = H >> 1, w = W >> 1;
  const int total = NC * h * w;
  const int idx = blockIdx.x * 256 + threadIdx.x;
  if (idx >= total) return;
  const int c = idx / (h * w);
  const int rem = idx - c * (h * w);
  const int r = rem / w, cl = rem - r * w;
  const float* ib = in + ((size_t)c * H + 2 * r) * W + 2 * cl;
  out[idx] = fmaxf(fmaxf(ib[0], ib[1]), fmaxf(ib[W], ib[W + 1]));
}

__global__ __launch_bounds__(256) void perc_k(const float* __restrict__ a,
                                              const float* __restrict__ b,
                                              float* __restrict__ acc, int N) {
  const int idx = blockIdx.x * 256 + threadIdx.x;
  float v = 0.f;
  if (idx < N) { const float d = a[idx] - b[idx]; v = d * d; }
  const float t = blockSum256(v);
  if (threadIdx.x == 0) atomicAdd(acc + ACC_PERC, t);
}

// ---------------- final combine ----------------
__global__ void final_k(const float* __restrict__ acc, float* __restrict__ out) {
  if (threadIdx.x != 0 || blockIdx.x != 0) return;
  const float NPIX = 2.f * 3.f * 224.f * 224.f;
  const float l1 = acc[ACC_L1] / NPIX;
  const float mse = acc[ACC_MSE] / NPIX;
  const float psnr = 40.f + 10.f * log10f(mse);
  const float cm = 1.f / (3.f * 224.f * 224.f);
  const float color = 0.5f * (fabsf(acc[ACC_ST0] - acc[ACC_SP0]) +
                              fabsf(acc[ACC_ST1] - acc[ACC_SP1])) * cm;
  const float ill = acc[ACC_HV] / 669.f + acc[ACC_WV] / 448.f;  // 2/B=1 folded in
  const float expl = acc[ACC_EXP] / 392.f;
  const float spat = acc[ACC_SPAT] / 6272.f;
  const float perc = acc[ACC_PERC] / 1605632.f;
  const float wms[5] = {0.0448f, 0.2856f, 0.3001f, 0.2363f, 0.1333f};
  const int ns[5] = {214, 102, 46, 18, 4};
  float msum = 0.f;
  for (int img = 0; img < 6; ++img) {
    float prod = 1.f;
    for (int s = 0; s < 5; ++s) {
      const float denom = (float)(ns[s] * ns[s]);
      float v = (s == 4) ? acc[ACC_SSIM + s * 12 + img] / denom
                         : acc[ACC_SSIM + s * 12 + 6 + img] / denom;
      v = fmaxf(v, 0.f);
      prod *= powf(v, wms[s]);
    }
    msum += prod;
  }
  const float msssim = msum / 6.f;
  // soft-histogram term skipped: |h1-h2| is an L1 distance of two normalized
  // distributions over 38.5M cells -> hist_l <= 5.2e-8, weighted 2.6e-9 (< fp32 ulp of result)
  out[0] = l1 + 0.06f * perc + 0.0083f * psnr + 0.25f * color +
           0.5f * (1.f - msssim) + 0.1f * expl + 0.1f * ill + 0.1f * spat;
}

extern "C" void kernel_launch(void* const* d_in, const int* in_sizes, int n_in,
                              void* d_out, int out_size, void* d_ws, size_t ws_size,
                              hipStream_t stream) {
  const float* yt = (const float*)d_in[0];
  const float* yp = (const float*)d_in[1];
  const float* W7[7]; const float* B7[7];
  for (int i = 0; i < 7; ++i) {   // dict order: y_true, y_pred, w0,b0,w1,b1,...
    W7[i] = (const float*)d_in[2 + 2 * i];
    B7[i] = (const float*)d_in[3 + 2 * i];
  }

  char* ws = (char*)d_ws;
  float* acc = (float*)ws;
  size_t off = 4096;
  float* A  = (float*)(ws + off); off += (size_t)64 * 224 * 224 * 4;  // 12.85 MB
  float* Bf = (float*)(ws + off); off += (size_t)64 * 224 * 224 * 4;  // 12.85 MB
  float* F1 = (float*)(ws + off); off += (size_t)256 * 56 * 56 * 4;   // 3.2 MB
  float* op = (float*)(ws + off); off += 2 * 56 * 56 * 4;
  float* ep = (float*)(ws + off); off += 2 * 56 * 56 * 4;
  if (ws_size < off) return;
  // scratch aliases used only BEFORE the VGG stage:
  float* tmp5 = A;                  // 5.75 MB needed, fits in A
  float* pyrX = Bf;                 // 99,960 floats
  float* pyrY = Bf + 100000;

  GW gw;
  {
    double vv[11]; double s = 0.0;
    for (int i = 0; i < 11; ++i) { const double c = i - 5.0; vv[i] = exp(-(c * c) / 4.5); s += vv[i]; }
    for (int i = 0; i < 11; ++i) gw.g[i] = (float)(vv[i] / s);
  }

  hipMemsetAsync(acc, 0, 512 * sizeof(float), stream);

  basic_stats<<<1176, 256, 0, stream>>>(yt, yp, acc);
  exposure_k<<<392, 256, 0, stream>>>(yp, acc);
  pool4_lum_k<<<25, 256, 0, stream>>>(yt, yp, op, ep);
  spat_k<<<25, 256, 0, stream>>>(op, ep, acc);

  // MS-SSIM over 5 scales (uses A/Bf as scratch, before VGG)
  const int dims[5] = {224, 112, 56, 28, 14};
  const int pyrOff[4] = {0, 75264, 94080, 98784};
  const float* Xs = yt; const float* Ys = yp;
  for (int s = 0; s < 5; ++s) {
    const int n = dims[s], m = n - 10;
    const int totV = 6 * m * n;
    gaussV_k<<<(totV + 255) / 256, 256, 0, stream>>>(Xs, Ys, tmp5, n, gw);
    dim3 gh((m * m + 255) / 256, 6);
    gaussH_ssim_k<<<gh, 256, 0, stream>>>(tmp5, acc, n, s, gw);
    if (s < 4) {
      const int hn = n >> 1;
      const int totD = 6 * hn * hn;
      float* nx = pyrX + pyrOff[s];
      float* ny = pyrY + pyrOff[s];
      down2_k<<<(totD + 255) / 256, 256, 0, stream>>>(Xs, nx, n);
      down2_k<<<(totD + 255) / 256, 256, 0, stream>>>(Ys, ny, n);
      Xs = nx; Ys = ny;
    }
  }

  // VGG19[:16] x2 inputs, per batch image (halves workspace, grids still saturate)
  for (int b = 0; b < 2; ++b) {
    for (int pass = 0; pass < 2; ++pass) {
      const float* src = (pass == 0 ? yt : yp) + (size_t)b * 3 * 224 * 224;
      conv3x3_relu<<<dim3(28, 28, 4),  dim3(8, 8, 4), 0, stream>>>(src, W7[0], B7[0], A, 3, 224, 224, 64);
      conv3x3_relu<<<dim3(28, 28, 4),  dim3(8, 8, 4), 0, stream>>>(A, W7[1], B7[1], Bf, 64, 224, 224, 64);
      maxpool2_k<<<(64 * 112 * 112 + 255) / 256, 256, 0, stream>>>(Bf, A, 64, 224, 224);
      conv3x3_relu<<<dim3(14, 14, 8),  dim3(8, 8, 4), 0, stream>>>(A, W7[2], B7[2], Bf, 64, 112, 112, 128);
      conv3x3_relu<<<dim3(14, 14, 8),  dim3(8, 8, 4), 0, stream>>>(Bf, W7[3], B7[3], A, 128, 112, 112, 128);
      maxpool2_k<<<(128 * 56 * 56 + 255) / 256, 256, 0, stream>>>(A, Bf, 128, 112, 112);
      conv3x3_relu<<<dim3(7, 7, 16),   dim3(8, 8, 4), 0, stream>>>(Bf, W7[4], B7[4], A, 128, 56, 56, 256);
      conv3x3_relu<<<dim3(7, 7, 16),   dim3(8, 8, 4), 0, stream>>>(A, W7[5], B7[5], Bf, 256, 56, 56, 256);
      float* dst = (pass == 0) ? F1 : A;
      conv3x3_relu<<<dim3(7, 7, 16),   dim3(8, 8, 4), 0, stream>>>(Bf, W7[6], B7[6], dst, 256, 56, 56, 256);
    }
    perc_k<<<3136, 256, 0, stream>>>(F1, A, acc, 802816);
  }

  final_k<<<1, 64, 0, stream>>>(acc, (float*)d_out);
}

// Round 2
// 1389.780 us; speedup vs baseline: 2.5299x; 2.5299x over previous
//
#include <hip/hip_runtime.h>
#include <cmath>

typedef __attribute__((ext_vector_type(8))) short  short8;
typedef __attribute__((ext_vector_type(4))) float  floatx4;

// Accumulator slots (floats) at start of workspace
#define ACC_L1   0
#define ACC_MSE  1
#define ACC_ST0  2
#define ACC_ST1  3
#define ACC_SP0  4
#define ACC_SP1  5
#define ACC_HV   6
#define ACC_WV   7
#define ACC_EXP  8
#define ACC_SPAT 9
#define ACC_PERC 10
#define ACC_SSIM 16   // + scale*12 + (cs?6:0) + img   (img = b*3+c)

struct GW { float g[11]; };

__device__ __forceinline__ float waveSum(float v) {
#pragma unroll
  for (int o = 32; o > 0; o >>= 1) v += __shfl_down(v, o, 64);
  return v;
}

__device__ __forceinline__ float blockSum256(float v) {
  __shared__ float red[4];
  const int tid = threadIdx.x;
  v = waveSum(v);
  __syncthreads();
  if ((tid & 63) == 0) red[tid >> 6] = v;
  __syncthreads();
  return red[0] + red[1] + red[2] + red[3];
}

__device__ __forceinline__ unsigned short f2bf(float f) {
  union { float f; unsigned int u; } v; v.f = f;
  const unsigned int u = v.u;
  return (unsigned short)((u + 0x7fffu + ((u >> 16) & 1u)) >> 16);
}
__device__ __forceinline__ float bf2f(unsigned short h) {
  union { unsigned int u; float f; } v; v.u = ((unsigned int)h) << 16;
  return v.f;
}

// ---------------- small loss terms ----------------

__global__ __launch_bounds__(256) void basic_stats(const float* __restrict__ yt,
                                                   const float* __restrict__ yp,
                                                   float* __restrict__ acc) {
  const int N = 2 * 3 * 224 * 224;
  const int idx = blockIdx.x * 256 + threadIdx.x;
  float l1 = 0.f, mse = 0.f, st0 = 0.f, st1 = 0.f, sp0 = 0.f, sp1 = 0.f, hv = 0.f, wv = 0.f;
  if (idx < N) {
    const float t = yt[idx], p = yp[idx];
    const float d = p - t;
    const float ad = fabsf(d);
    l1 = (ad < 1.f) ? 0.5f * d * d : ad - 0.5f;
    mse = d * d;
    const int b = idx / (3 * 224 * 224);
    if (b == 0) { st0 = t; sp0 = p; } else { st1 = t; sp1 = p; }
    const int w = idx % 224;
    const int h = (idx / 224) % 224;
    if (h < 223) { const float dv = yp[idx + 224] - p; hv = dv * dv; }
    if (w < 223) { const float dw = yp[idx + 1] - p; wv = dw * dw; }
  }
  float s;
  s = blockSum256(l1);  if (threadIdx.x == 0) atomicAdd(acc + ACC_L1, s);
  s = blockSum256(mse); if (threadIdx.x == 0) atomicAdd(acc + ACC_MSE, s);
  s = blockSum256(st0); if (threadIdx.x == 0) atomicAdd(acc + ACC_ST0, s);
  s = blockSum256(st1); if (threadIdx.x == 0) atomicAdd(acc + ACC_ST1, s);
  s = blockSum256(sp0); if (threadIdx.x == 0) atomicAdd(acc + ACC_SP0, s);
  s = blockSum256(sp1); if (threadIdx.x == 0) atomicAdd(acc + ACC_SP1, s);
  s = blockSum256(hv);  if (threadIdx.x == 0) atomicAdd(acc + ACC_HV, s);
  s = blockSum256(wv);  if (threadIdx.x == 0) atomicAdd(acc + ACC_WV, s);
}

__global__ __launch_bounds__(256) void exposure_k(const float* __restrict__ yp,
                                                  float* __restrict__ acc) {
  const int blk = blockIdx.x;
  const int b = blk / 196;
  const int rem = blk - b * 196;
  const int py = rem / 14, px = rem - py * 14;
  float s = 0.f;
  for (int e = threadIdx.x; e < 768; e += 256) {
    const int c = e >> 8;
    const int rr = (e >> 4) & 15;
    const int cc = e & 15;
    s += yp[(((size_t)b * 3 + c) * 224 + py * 16 + rr) * 224 + px * 16 + cc];
  }
  const float t = blockSum256(s);
  if (threadIdx.x == 0) {
    const float m = t * (1.f / 768.f) - 0.6f;
    atomicAdd(acc + ACC_EXP, m * m);
  }
}

__global__ __launch_bounds__(256) void pool4_lum_k(const float* __restrict__ yt,
                                                   const float* __restrict__ yp,
                                                   float* __restrict__ op,
                                                   float* __restrict__ ep) {
  const int idx = blockIdx.x * 256 + threadIdx.x;
  if (idx >= 2 * 56 * 56) return;
  const int b = idx / 3136;
  const int rem = idx - b * 3136;
  const int r = rem / 56, cl = rem - r * 56;
  float so = 0.f, se = 0.f;
  for (int c = 0; c < 3; ++c)
    for (int dy = 0; dy < 4; ++dy)
      for (int dx = 0; dx < 4; ++dx) {
        const size_t off = (((size_t)b * 3 + c) * 224 + (r * 4 + dy)) * 224 + cl * 4 + dx;
        so += yt[off]; se += yp[off];
      }
  op[idx] = so * (1.f / 48.f);
  ep[idx] = se * (1.f / 48.f);
}

__global__ __launch_bounds__(256) void spat_k(const float* __restrict__ op,
                                              const float* __restrict__ ep,
                                              float* __restrict__ acc) {
  const int idx = blockIdx.x * 256 + threadIdx.x;
  float v = 0.f;
  if (idx < 6272) {
    const int rem = idx % 3136;
    const int r = rem / 56, cl = rem - r * 56;
    const float oc = op[idx], ec = ep[idx];
    const float ol = (cl > 0)  ? op[idx - 1]  : 0.f;
    const float el = (cl > 0)  ? ep[idx - 1]  : 0.f;
    const float orr = (cl < 55) ? op[idx + 1]  : 0.f;
    const float er  = (cl < 55) ? ep[idx + 1]  : 0.f;
    const float ou = (r > 0)   ? op[idx - 56] : 0.f;
    const float eu = (r > 0)   ? ep[idx - 56] : 0.f;
    const float od = (r < 55)  ? op[idx + 56] : 0.f;
    const float ed = (r < 55)  ? ep[idx + 56] : 0.f;
    float d;
    d = (oc - ol) - (ec - el);   v += d * d;
    d = (oc - orr) - (ec - er);  v += d * d;
    d = (oc - ou) - (ec - eu);   v += d * d;
    d = (oc - od) - (ec - ed);   v += d * d;
  }
  const float t = blockSum256(v);
  if (threadIdx.x == 0) atomicAdd(acc + ACC_SPAT, t);
}

// ---------------- MS-SSIM ----------------

__global__ __launch_bounds__(256) void gaussV_k(const float* __restrict__ X,
                                                const float* __restrict__ Y,
                                                float* __restrict__ tmp, int n, GW gw) {
  const int m = n - 10;
  const int total = 6 * m * n;
  const int idx = blockIdx.x * 256 + threadIdx.x;
  if (idx >= total) return;
  const int img = idx / (m * n);
  const int rem = idx - img * (m * n);
  const int r = rem / n, cl = rem - r * n;
  const float* xb = X + (size_t)img * n * n + (size_t)r * n + cl;
  const float* yb = Y + (size_t)img * n * n + (size_t)r * n + cl;
  float sx = 0.f, sy = 0.f, sxx = 0.f, syy = 0.f, sxy = 0.f;
#pragma unroll
  for (int t = 0; t < 11; ++t) {
    const float xv = xb[(size_t)t * n];
    const float yv = yb[(size_t)t * n];
    const float g = gw.g[t];
    sx += g * xv; sy += g * yv;
    sxx += g * xv * xv; syy += g * yv * yv; sxy += g * xv * yv;
  }
  const size_t st = (size_t)6 * m * n;
  tmp[idx] = sx; tmp[st + idx] = sy;
  tmp[2 * st + idx] = sxx; tmp[3 * st + idx] = syy; tmp[4 * st + idx] = sxy;
}

__global__ __launch_bounds__(256) void gaussH_ssim_k(const float* __restrict__ tmp,
                                                     float* __restrict__ acc,
                                                     int n, int scale, GW gw) {
  const int m = n - 10;
  const int img = blockIdx.y;
  const int pid = blockIdx.x * 256 + threadIdx.x;
  float sv = 0.f, cv = 0.f;
  if (pid < m * m) {
    const int r = pid / m, cl = pid - r * m;
    const size_t st = (size_t)6 * m * n;
    const float* t0 = tmp + (size_t)img * m * n + (size_t)r * n + cl;
    float mu1 = 0.f, mu2 = 0.f, e11 = 0.f, e22 = 0.f, e12 = 0.f;
#pragma unroll
    for (int t = 0; t < 11; ++t) {
      const float g = gw.g[t];
      mu1 += g * t0[t];
      mu2 += g * t0[st + t];
      e11 += g * t0[2 * st + t];
      e22 += g * t0[3 * st + t];
      e12 += g * t0[4 * st + t];
    }
    const float C1 = 1e-4f, C2 = 9e-4f;
    const float s11 = e11 - mu1 * mu1;
    const float s22 = e22 - mu2 * mu2;
    const float s12 = e12 - mu1 * mu2;
    cv = (2.f * s12 + C2) / (s11 + s22 + C2);
    sv = ((2.f * mu1 * mu2 + C1) / (mu1 * mu1 + mu2 * mu2 + C1)) * cv;
  }
  float t = blockSum256(sv);
  if (threadIdx.x == 0) atomicAdd(acc + ACC_SSIM + scale * 12 + img, t);
  t = blockSum256(cv);
  if (threadIdx.x == 0) atomicAdd(acc + ACC_SSIM + scale * 12 + 6 + img, t);
}

__global__ __launch_bounds__(256) void down2_k(const float* __restrict__ X,
                                               float* __restrict__ O, int n) {
  const int h = n >> 1;
  const int total = 6 * h * h;
  const int idx = blockIdx.x * 256 + threadIdx.x;
  if (idx >= total) return;
  const int img = idx / (h * h);
  const int rem = idx - img * (h * h);
  const int r = rem / h, cl = rem - r * h;
  const float* xb = X + (size_t)img * n * n + (size_t)(2 * r) * n + 2 * cl;
  O[idx] = 0.25f * (xb[0] + xb[1] + xb[n] + xb[n + 1]);
}

// ---------------- VGG ----------------

// weight transform: wt[cout][cin][3][3] fp32 -> dst[cout][tap][cin] bf16
__global__ __launch_bounds__(256) void wt_transform(const float* __restrict__ wt,
                                                    unsigned short* __restrict__ dst,
                                                    int Cout, int Cin) {
  const int idx = blockIdx.x * 256 + threadIdx.x;
  const int total = Cout * 9 * Cin;
  if (idx >= total) return;
  const int cin = idx % Cin;
  const int t = idx / Cin;
  const int tap = t % 9;
  const int cout = t / 9;
  dst[idx] = f2bf(wt[((size_t)cout * Cin + cin) * 9 + tap]);
}

// zero the 1-px border of a padded NHWC buffer (H+2, W+2, C)
__global__ __launch_bounds__(256) void zero_border(unsigned short* __restrict__ buf,
                                                   int H, int W, int C) {
  const int Wp = W + 2;
  const int rowE = Wp * C;
  const int total = 2 * rowE + 2 * H * C;
  const int idx = blockIdx.x * 256 + threadIdx.x;
  if (idx >= total) return;
  size_t o;
  if (idx < rowE) o = idx;                                   // y = 0
  else if (idx < 2 * rowE) o = (size_t)(H + 1) * rowE + (idx - rowE);  // y = H+1
  else {
    const int k = idx - 2 * rowE;
    const int y = k / (2 * C) + 1;
    const int r = k % (2 * C);
    const int x = (r < C) ? 0 : (W + 1);
    const int c = (r < C) ? r : (r - C);
    o = (size_t)y * rowE + (size_t)x * C + c;
  }
  buf[o] = 0;
}

// layer1: Cin=3 direct conv, NCHW fp32 in -> padded NHWC bf16 out (Cout=64)
__global__ __launch_bounds__(256) void conv1_k(
    const float* __restrict__ in, const float* __restrict__ wt,
    const float* __restrict__ bias, unsigned short* __restrict__ out, int HW) {
  __shared__ float sIn[3][10][12];
  const int tx = threadIdx.x, ty = threadIdx.y, tz = threadIdx.z;
  const int tid = (tz << 6) | (ty << 3) | tx;
  const int x0 = blockIdx.x << 3, y0 = blockIdx.y << 3;
  const int x = x0 + tx, y = y0 + ty;
  int wrow = (blockIdx.z * 16 + tz * 4) * 27;
  wrow = __builtin_amdgcn_readfirstlane(wrow);

  for (int el = tid; el < 300; el += 256) {
    const int ci = el / 100;
    const int rem = el - ci * 100;
    const int r = rem / 10, cl = rem - r * 10;
    const int gy = y0 - 1 + r, gx = x0 - 1 + cl;
    float v = 0.f;
    if (gy >= 0 && gy < HW && gx >= 0 && gx < HW)
      v = in[((size_t)ci * HW + gy) * HW + gx];
    sIn[ci][r][cl] = v;
  }
  __syncthreads();

  float a0 = 0.f, a1 = 0.f, a2 = 0.f, a3 = 0.f;
#pragma unroll
  for (int ci = 0; ci < 3; ++ci) {
    float xv[9];
#pragma unroll
    for (int ky = 0; ky < 3; ++ky)
#pragma unroll
      for (int kx = 0; kx < 3; ++kx)
        xv[ky * 3 + kx] = sIn[ci][ty + ky][tx + kx];
    const float* wp = wt + wrow + ci * 9;
#pragma unroll
    for (int k = 0; k < 9; ++k) {
      a0 = fmaf(xv[k], wp[k], a0);
      a1 = fmaf(xv[k], wp[27 + k], a1);
      a2 = fmaf(xv[k], wp[54 + k], a2);
      a3 = fmaf(xv[k], wp[81 + k], a3);
    }
  }
  const int coB = blockIdx.z * 16 + tz * 4;
  const size_t o = ((size_t)(y + 1) * (HW + 2) + (x + 1)) * 64 + coB;
  uint2 pk;
  pk.x = (unsigned int)f2bf(fmaxf(a0 + bias[coB + 0], 0.f)) |
         ((unsigned int)f2bf(fmaxf(a1 + bias[coB + 1], 0.f)) << 16);
  pk.y = (unsigned int)f2bf(fmaxf(a2 + bias[coB + 2], 0.f)) |
         ((unsigned int)f2bf(fmaxf(a3 + bias[coB + 3], 0.f)) << 16);
  *(uint2*)(out + o) = pk;
}

// implicit-GEMM conv3x3 SAME + bias + relu via mfma_f32_16x16x32_bf16.
// in: padded NHWC bf16 (H+2, W+2, CIN), wtp: [cout][9][CIN] bf16,
// out: padded NHWC bf16 (H+2, W+2, Cout).
// block = 4 waves: wave(wc,wp) computes (WTM*16 cout) x (WTN*16 px) via MFMA subtiles.
// A-frag: W[cout=lane&15][k=quad*8+j], B-frag: In[px=lane&15][k=quad*8+j],
// C: row(cout)=quad*4+reg, col(px)=lane&15   [verified layouts, learn_hip m89/m120]
template<int CIN, int WTM, int WTN>
__global__ __launch_bounds__(256) void conv_mfma(
    const unsigned short* __restrict__ in, const unsigned short* __restrict__ wtp,
    const float* __restrict__ bias, unsigned short* __restrict__ out,
    int W, int Cout) {
  const int tid = threadIdx.x;
  const int lane = tid & 63;
  const int wave = tid >> 6;
  const int quad = lane >> 4;
  const int lr = lane & 15;
  const int wc = wave & 1;
  const int wp = wave >> 1;
  const int y = blockIdx.y;
  const int Wp = W + 2;
  const int xw = blockIdx.x * (WTN * 32) + wp * (WTN * 16);
  const int cob = blockIdx.z * (WTM * 32) + wc * (WTM * 16);

  floatx4 acc[WTM][WTN];
#pragma unroll
  for (int m = 0; m < WTM; ++m)
#pragma unroll
    for (int n = 0; n < WTN; ++n) acc[m][n] = (floatx4){0.f, 0.f, 0.f, 0.f};

  const unsigned short* aln[WTM];
#pragma unroll
  for (int m = 0; m < WTM; ++m)
    aln[m] = wtp + (size_t)(cob + m * 16 + lr) * (9 * CIN) + quad * 8;
  const unsigned short* bbase = in + ((size_t)y * Wp + xw + lr) * CIN + quad * 8;

#pragma unroll
  for (int tap = 0; tap < 9; ++tap) {
    const int dy = tap / 3, dx = tap - dy * 3;
    const unsigned short* bt = bbase + (dy * Wp + dx) * CIN;
#pragma unroll
    for (int c0 = 0; c0 < CIN / 32; ++c0) {
      short8 af[WTM], bfr[WTN];
#pragma unroll
      for (int m = 0; m < WTM; ++m)
        af[m] = *(const short8*)(aln[m] + tap * CIN + c0 * 32);
#pragma unroll
      for (int n = 0; n < WTN; ++n)
        bfr[n] = *(const short8*)(bt + n * 16 * CIN + c0 * 32);
#pragma unroll
      for (int m = 0; m < WTM; ++m)
#pragma unroll
        for (int n = 0; n < WTN; ++n)
          acc[m][n] = __builtin_amdgcn_mfma_f32_16x16x32_bf16(af[m], bfr[n], acc[m][n], 0, 0, 0);
    }
  }

#pragma unroll
  for (int m = 0; m < WTM; ++m) {
    const int cb = cob + m * 16 + quad * 4;
#pragma unroll
    for (int n = 0; n < WTN; ++n) {
      const int px = xw + n * 16 + lr;
      if (px < W) {
        const float v0 = fmaxf(acc[m][n].x + bias[cb + 0], 0.f);
        const float v1 = fmaxf(acc[m][n].y + bias[cb + 1], 0.f);
        const float v2 = fmaxf(acc[m][n].z + bias[cb + 2], 0.f);
        const float v3 = fmaxf(acc[m][n].w + bias[cb + 3], 0.f);
        uint2 pk;
        pk.x = (unsigned int)f2bf(v0) | ((unsigned int)f2bf(v1) << 16);
        pk.y = (unsigned int)f2bf(v2) | ((unsigned int)f2bf(v3) << 16);
        *(uint2*)(out + ((size_t)(y + 1) * Wp + px + 1) * Cout + cb) = pk;
      }
    }
  }
}

// 2x2 maxpool on padded NHWC bf16: (2Ho+2,2Wo+2,C) -> interior of (Ho+2,Wo+2,C)
__global__ __launch_bounds__(256) void pool_nhwc(const unsigned short* __restrict__ in,
                                                 unsigned short* __restrict__ out,
                                                 int Ho, int Wo, int C) {
  const int total = Ho * Wo * C;
  const int idx = blockIdx.x * 256 + threadIdx.x;
  if (idx >= total) return;
  const int c = idx % C;
  const int p = idx / C;
  const int x = p % Wo, y = p / Wo;
  const int Wi = 2 * Wo + 2;
  const unsigned short* ib = in + ((size_t)(2 * y + 1) * Wi + (2 * x + 1)) * C + c;
  const float a = bf2f(ib[0]), b = bf2f(ib[C]);
  const float d = bf2f(ib[(size_t)Wi * C]), e = bf2f(ib[(size_t)Wi * C + C]);
  out[((size_t)(y + 1) * (Wo + 2) + x + 1) * C + c] = f2bf(fmaxf(fmaxf(a, b), fmaxf(d, e)));
}

// perceptual: sum (f1-f2)^2 over interior of padded (58,58,256) bf16 buffers
__global__ __launch_bounds__(256) void perc_k(const unsigned short* __restrict__ f1,
                                              const unsigned short* __restrict__ f2,
                                              float* __restrict__ acc) {
  const int total = 56 * 56 * 256;
  const int idx = blockIdx.x * 256 + threadIdx.x;
  float v = 0.f;
  if (idx < total) {
    const int c = idx & 255;
    const int p = idx >> 8;
    const int x = p % 56, y = p / 56;
    const size_t o = ((size_t)(y + 1) * 58 + x + 1) * 256 + c;
    const float d = bf2f(f1[o]) - bf2f(f2[o]);
    v = d * d;
  }
  const float t = blockSum256(v);
  if (threadIdx.x == 0) atomicAdd(acc + ACC_PERC, t);
}

// ---------------- final combine ----------------
__global__ void final_k(const float* __restrict__ acc, float* __restrict__ out) {
  if (threadIdx.x != 0 || blockIdx.x != 0) return;
  const float NPIX = 2.f * 3.f * 224.f * 224.f;
  const float l1 = acc[ACC_L1] / NPIX;
  const float mse = acc[ACC_MSE] / NPIX;
  const float psnr = 40.f + 10.f * log10f(mse);
  const float cm = 1.f / (3.f * 224.f * 224.f);
  const float color = 0.5f * (fabsf(acc[ACC_ST0] - acc[ACC_SP0]) +
                              fabsf(acc[ACC_ST1] - acc[ACC_SP1])) * cm;
  const float ill = acc[ACC_HV] / 669.f + acc[ACC_WV] / 448.f;
  const float expl = acc[ACC_EXP] / 392.f;
  const float spat = acc[ACC_SPAT] / 6272.f;
  const float perc = acc[ACC_PERC] / 1605632.f;
  const float wms[5] = {0.0448f, 0.2856f, 0.3001f, 0.2363f, 0.1333f};
  const int ns[5] = {214, 102, 46, 18, 4};
  float msum = 0.f;
  for (int img = 0; img < 6; ++img) {
    float prod = 1.f;
    for (int s = 0; s < 5; ++s) {
      const float denom = (float)(ns[s] * ns[s]);
      float v = (s == 4) ? acc[ACC_SSIM + s * 12 + img] / denom
                         : acc[ACC_SSIM + s * 12 + 6 + img] / denom;
      v = fmaxf(v, 0.f);
      prod *= powf(v, wms[s]);
    }
    msum += prod;
  }
  const float msssim = msum / 6.f;
  out[0] = l1 + 0.06f * perc + 0.0083f * psnr + 0.25f * color +
           0.5f * (1.f - msssim) + 0.1f * expl + 0.1f * ill + 0.1f * spat;
}

extern "C" void kernel_launch(void* const* d_in, const int* in_sizes, int n_in,
                              void* d_out, int out_size, void* d_ws, size_t ws_size,
                              hipStream_t stream) {
  const float* yt = (const float*)d_in[0];
  const float* yp = (const float*)d_in[1];
  const float* W7[7]; const float* B7[7];
  for (int i = 0; i < 7; ++i) {
    W7[i] = (const float*)d_in[2 + 2 * i];
    B7[i] = (const float*)d_in[3 + 2 * i];
  }

  char* ws = (char*)d_ws;
  float* acc = (float*)ws;
  size_t off = 4096;
  float* op = (float*)(ws + off); off += 2 * 3136 * 4;
  float* ep = (float*)(ws + off); off += 2 * 3136 * 4;
  off = (off + 255) & ~(size_t)255;
  unsigned short* P0 = (unsigned short*)(ws + off); off += (size_t)226 * 226 * 64 * 2 + 16384;
  off = (off + 255) & ~(size_t)255;
  unsigned short* P1 = (unsigned short*)(ws + off); off += (size_t)226 * 226 * 64 * 2 + 16384;
  off = (off + 255) & ~(size_t)255;
  unsigned short* FH = (unsigned short*)(ws + off); off += (size_t)58 * 58 * 256 * 2 + 16384;
  off = (off + 255) & ~(size_t)255;
  unsigned short* WT = (unsigned short*)(ws + off); off += (size_t)1732608 * 2;
  if (ws_size < off) return;

  // aliases used only BEFORE the VGG stage
  float* tmp5 = (float*)P0;            // 5.75 MB needed, P0 = 6.55 MB
  float* pyrX = (float*)P1;            // 100k floats
  float* pyrY = (float*)P1 + 100000;

  GW gw;
  {
    double vv[11]; double s = 0.0;
    for (int i = 0; i < 11; ++i) { const double c = i - 5.0; vv[i] = exp(-(c * c) / 4.5); s += vv[i]; }
    for (int i = 0; i < 11; ++i) gw.g[i] = (float)(vv[i] / s);
  }

  hipMemsetAsync(acc, 0, 512 * sizeof(float), stream);

  // weight transforms (once, reused by all 4 VGG runs)
  const int co[7] = {64, 64, 128, 128, 256, 256, 256};
  const int ci[7] = {3, 64, 64, 128, 128, 256, 256};
  size_t wtOff[7]; size_t e = 0;
  for (int i = 1; i < 7; ++i) { wtOff[i] = e; e += (size_t)co[i] * 9 * ci[i]; }
  for (int i = 1; i < 7; ++i) {
    const int tot = co[i] * 9 * ci[i];
    wt_transform<<<(tot + 255) / 256, 256, 0, stream>>>(W7[i], WT + wtOff[i], co[i], ci[i]);
  }

  basic_stats<<<1176, 256, 0, stream>>>(yt, yp, acc);
  exposure_k<<<392, 256, 0, stream>>>(yp, acc);
  pool4_lum_k<<<25, 256, 0, stream>>>(yt, yp, op, ep);
  spat_k<<<25, 256, 0, stream>>>(op, ep, acc);

  // MS-SSIM over 5 scales (uses P0/P1 as scratch, strictly before VGG)
  const int dims[5] = {224, 112, 56, 28, 14};
  const int pyrOff[4] = {0, 75264, 94080, 98784};
  const float* Xs = yt; const float* Ys = yp;
  for (int s = 0; s < 5; ++s) {
    const int n = dims[s], m = n - 10;
    const int totV = 6 * m * n;
    gaussV_k<<<(totV + 255) / 256, 256, 0, stream>>>(Xs, Ys, tmp5, n, gw);
    dim3 gh((m * m + 255) / 256, 6);
    gaussH_ssim_k<<<gh, 256, 0, stream>>>(tmp5, acc, n, s, gw);
    if (s < 4) {
      const int hn = n >> 1;
      const int totD = 6 * hn * hn;
      float* nx = pyrX + pyrOff[s];
      float* ny = pyrY + pyrOff[s];
      down2_k<<<(totD + 255) / 256, 256, 0, stream>>>(Xs, nx, n);
      down2_k<<<(totD + 255) / 256, 256, 0, stream>>>(Ys, ny, n);
      Xs = nx; Ys = ny;
    }
  }

  auto zb = [&](unsigned short* buf, int H, int W, int C) {
    const int tot = 2 * (W + 2) * C + 2 * H * C;
    zero_border<<<(tot + 255) / 256, 256, 0, stream>>>(buf, H, W, C);
  };

  // VGG19[:16] on 4 images (2 batch x {y_true, y_pred})
  for (int b = 0; b < 2; ++b) {
    for (int pass = 0; pass < 2; ++pass) {
      const float* src = (pass == 0 ? yt : yp) + (size_t)b * 3 * 224 * 224;
      conv1_k<<<dim3(28, 28, 4), dim3(8, 8, 4), 0, stream>>>(src, W7[0], B7[0], P0, 224);
      zb(P0, 224, 224, 64);
      conv_mfma<64, 2, 2><<<dim3(4, 224, 1), 256, 0, stream>>>(P0, WT + wtOff[1], B7[1], P1, 224, 64);
      pool_nhwc<<<(112 * 112 * 64 + 255) / 256, 256, 0, stream>>>(P1, P0, 112, 112, 64);
      zb(P0, 112, 112, 64);
      conv_mfma<64, 2, 2><<<dim3(2, 112, 2), 256, 0, stream>>>(P0, WT + wtOff[2], B7[2], P1, 112, 128);
      zb(P1, 112, 112, 128);
      conv_mfma<128, 2, 2><<<dim3(2, 112, 2), 256, 0, stream>>>(P1, WT + wtOff[3], B7[3], P0, 112, 128);
      pool_nhwc<<<(56 * 56 * 128 + 255) / 256, 256, 0, stream>>>(P0, P1, 56, 56, 128);
      zb(P1, 56, 56, 128);
      conv_mfma<128, 2, 1><<<dim3(2, 56, 4), 256, 0, stream>>>(P1, WT + wtOff[4], B7[4], P0, 56, 256);
      zb(P0, 56, 56, 256);
      conv_mfma<256, 2, 1><<<dim3(2, 56, 4), 256, 0, stream>>>(P0, WT + wtOff[5], B7[5], P1, 56, 256);
      zb(P1, 56, 56, 256);
      unsigned short* dst = (pass == 0) ? FH : P0;
      conv_mfma<256, 2, 1><<<dim3(2, 56, 4), 256, 0, stream>>>(P1, WT + wtOff[6], B7[6], dst, 56, 256);
    }
    perc_k<<<(56 * 56 * 256 + 255) / 256, 256, 0, stream>>>(FH, P0, acc);
  }

  final_k<<<1, 64, 0, stream>>>(acc, (float*)d_out);
}

// Round 3
// 1115.516 us; speedup vs baseline: 3.1519x; 1.2459x over previous
//
#include <hip/hip_runtime.h>
#include <cmath>

typedef __attribute__((ext_vector_type(8))) short  short8;
typedef __attribute__((ext_vector_type(4))) float  floatx4;

// Accumulator slots spread 64B apart to avoid same-cacheline atomic serialization.
// base slot i -> acc[i*16]; ssim slot -> acc[256 + (scale*12 + cs*6 + img)*16]
#define SLOT(i) ((i) * 16)
#define ACC_L1   0
#define ACC_MSE  1
#define ACC_ST0  2
#define ACC_ST1  3
#define ACC_SP0  4
#define ACC_SP1  5
#define ACC_HV   6
#define ACC_WV   7
#define ACC_EXP  8
#define ACC_SPAT 9
#define ACC_PERC 10
#define SSIM_SLOT(scale, cs, img) (256 + ((scale) * 12 + (cs) * 6 + (img)) * 16)

struct GW { float g[11]; };

__device__ __forceinline__ float waveSum(float v) {
#pragma unroll
  for (int o = 32; o > 0; o >>= 1) v += __shfl_down(v, o, 64);
  return v;
}

__device__ __forceinline__ float blockSum256(float v) {
  __shared__ float red[4];
  const int tid = threadIdx.x;
  v = waveSum(v);
  __syncthreads();
  if ((tid & 63) == 0) red[tid >> 6] = v;
  __syncthreads();
  return red[0] + red[1] + red[2] + red[3];
}

__device__ __forceinline__ unsigned short f2bf(float f) {
  union { float f; unsigned int u; } v; v.f = f;
  const unsigned int u = v.u;
  return (unsigned short)((u + 0x7fffu + ((u >> 16) & 1u)) >> 16);
}
__device__ __forceinline__ float bf2f(unsigned short h) {
  union { unsigned int u; float f; } v; v.u = ((unsigned int)h) << 16;
  return v.f;
}

// ---------------- small loss terms ----------------

// grid-stride over N with 256 blocks; 8 atomics/block to 8 separate cache lines.
__global__ __launch_bounds__(256) void basic_stats(const float* __restrict__ yt,
                                                   const float* __restrict__ yp,
                                                   float* __restrict__ acc) {
  const int N = 2 * 3 * 224 * 224;
  float l1 = 0.f, mse = 0.f, st0 = 0.f, st1 = 0.f, sp0 = 0.f, sp1 = 0.f, hv = 0.f, wv = 0.f;
  for (int idx = blockIdx.x * 256 + threadIdx.x; idx < N; idx += 256 * 256) {
    const float t = yt[idx], p = yp[idx];
    const float d = p - t;
    const float ad = fabsf(d);
    l1 += (ad < 1.f) ? 0.5f * d * d : ad - 0.5f;
    mse += d * d;
    if (idx < 3 * 224 * 224) { st0 += t; sp0 += p; } else { st1 += t; sp1 += p; }
    const int w = idx % 224;
    const int h = (idx / 224) % 224;
    if (h < 223) { const float dv = yp[idx + 224] - p; hv += dv * dv; }
    if (w < 223) { const float dw = yp[idx + 1] - p; wv += dw * dw; }
  }
  float s;
  s = blockSum256(l1);  if (threadIdx.x == 0) atomicAdd(acc + SLOT(ACC_L1), s);
  s = blockSum256(mse); if (threadIdx.x == 0) atomicAdd(acc + SLOT(ACC_MSE), s);
  s = blockSum256(st0); if (threadIdx.x == 0) atomicAdd(acc + SLOT(ACC_ST0), s);
  s = blockSum256(st1); if (threadIdx.x == 0) atomicAdd(acc + SLOT(ACC_ST1), s);
  s = blockSum256(sp0); if (threadIdx.x == 0) atomicAdd(acc + SLOT(ACC_SP0), s);
  s = blockSum256(sp1); if (threadIdx.x == 0) atomicAdd(acc + SLOT(ACC_SP1), s);
  s = blockSum256(hv);  if (threadIdx.x == 0) atomicAdd(acc + SLOT(ACC_HV), s);
  s = blockSum256(wv);  if (threadIdx.x == 0) atomicAdd(acc + SLOT(ACC_WV), s);
}

__global__ __launch_bounds__(256) void exposure_k(const float* __restrict__ yp,
                                                  float* __restrict__ acc) {
  const int blk = blockIdx.x;
  const int b = blk / 196;
  const int rem = blk - b * 196;
  const int py = rem / 14, px = rem - py * 14;
  float s = 0.f;
  for (int e = threadIdx.x; e < 768; e += 256) {
    const int c = e >> 8;
    const int rr = (e >> 4) & 15;
    const int cc = e & 15;
    s += yp[(((size_t)b * 3 + c) * 224 + py * 16 + rr) * 224 + px * 16 + cc];
  }
  const float t = blockSum256(s);
  if (threadIdx.x == 0) {
    const float m = t * (1.f / 768.f) - 0.6f;
    atomicAdd(acc + SLOT(ACC_EXP), m * m);
  }
}

__global__ __launch_bounds__(256) void pool4_lum_k(const float* __restrict__ yt,
                                                   const float* __restrict__ yp,
                                                   float* __restrict__ op,
                                                   float* __restrict__ ep) {
  const int idx = blockIdx.x * 256 + threadIdx.x;
  if (idx >= 2 * 56 * 56) return;
  const int b = idx / 3136;
  const int rem = idx - b * 3136;
  const int r = rem / 56, cl = rem - r * 56;
  float so = 0.f, se = 0.f;
  for (int c = 0; c < 3; ++c)
    for (int dy = 0; dy < 4; ++dy)
      for (int dx = 0; dx < 4; ++dx) {
        const size_t off = (((size_t)b * 3 + c) * 224 + (r * 4 + dy)) * 224 + cl * 4 + dx;
        so += yt[off]; se += yp[off];
      }
  op[idx] = so * (1.f / 48.f);
  ep[idx] = se * (1.f / 48.f);
}

__global__ __launch_bounds__(256) void spat_k(const float* __restrict__ op,
                                              const float* __restrict__ ep,
                                              float* __restrict__ acc) {
  const int idx = blockIdx.x * 256 + threadIdx.x;
  float v = 0.f;
  if (idx < 6272) {
    const int rem = idx % 3136;
    const int r = rem / 56, cl = rem - r * 56;
    const float oc = op[idx], ec = ep[idx];
    const float ol = (cl > 0)  ? op[idx - 1]  : 0.f;
    const float el = (cl > 0)  ? ep[idx - 1]  : 0.f;
    const float orr = (cl < 55) ? op[idx + 1]  : 0.f;
    const float er  = (cl < 55) ? ep[idx + 1]  : 0.f;
    const float ou = (r > 0)   ? op[idx - 56] : 0.f;
    const float eu = (r > 0)   ? ep[idx - 56] : 0.f;
    const float od = (r < 55)  ? op[idx + 56] : 0.f;
    const float ed = (r < 55)  ? ep[idx + 56] : 0.f;
    float d;
    d = (oc - ol) - (ec - el);   v += d * d;
    d = (oc - orr) - (ec - er);  v += d * d;
    d = (oc - ou) - (ec - eu);   v += d * d;
    d = (oc - od) - (ec - ed);   v += d * d;
  }
  const float t = blockSum256(v);
  if (threadIdx.x == 0) atomicAdd(acc + SLOT(ACC_SPAT), t);
}

// ---------------- MS-SSIM ----------------

__global__ __launch_bounds__(256) void gaussV_k(const float* __restrict__ X,
                                                const float* __restrict__ Y,
                                                float* __restrict__ tmp, int n, GW gw) {
  const int m = n - 10;
  const int total = 6 * m * n;
  const int idx = blockIdx.x * 256 + threadIdx.x;
  if (idx >= total) return;
  const int img = idx / (m * n);
  const int rem = idx - img * (m * n);
  const int r = rem / n, cl = rem - r * n;
  const float* xb = X + (size_t)img * n * n + (size_t)r * n + cl;
  const float* yb = Y + (size_t)img * n * n + (size_t)r * n + cl;
  float sx = 0.f, sy = 0.f, sxx = 0.f, syy = 0.f, sxy = 0.f;
#pragma unroll
  for (int t = 0; t < 11; ++t) {
    const float xv = xb[(size_t)t * n];
    const float yv = yb[(size_t)t * n];
    const float g = gw.g[t];
    sx += g * xv; sy += g * yv;
    sxx += g * xv * xv; syy += g * yv * yv; sxy += g * xv * yv;
  }
  const size_t st = (size_t)6 * m * n;
  tmp[idx] = sx; tmp[st + idx] = sy;
  tmp[2 * st + idx] = sxx; tmp[3 * st + idx] = syy; tmp[4 * st + idx] = sxy;
}

__global__ __launch_bounds__(256) void gaussH_ssim_k(const float* __restrict__ tmp,
                                                     float* __restrict__ acc,
                                                     int n, int scale, GW gw) {
  const int m = n - 10;
  const int img = blockIdx.y;
  const int pid = blockIdx.x * 256 + threadIdx.x;
  float sv = 0.f, cv = 0.f;
  if (pid < m * m) {
    const int r = pid / m, cl = pid - r * m;
    const size_t st = (size_t)6 * m * n;
    const float* t0 = tmp + (size_t)img * m * n + (size_t)r * n + cl;
    float mu1 = 0.f, mu2 = 0.f, e11 = 0.f, e22 = 0.f, e12 = 0.f;
#pragma unroll
    for (int t = 0; t < 11; ++t) {
      const float g = gw.g[t];
      mu1 += g * t0[t];
      mu2 += g * t0[st + t];
      e11 += g * t0[2 * st + t];
      e22 += g * t0[3 * st + t];
      e12 += g * t0[4 * st + t];
    }
    const float C1 = 1e-4f, C2 = 9e-4f;
    const float s11 = e11 - mu1 * mu1;
    const float s22 = e22 - mu2 * mu2;
    const float s12 = e12 - mu1 * mu2;
    cv = (2.f * s12 + C2) / (s11 + s22 + C2);
    sv = ((2.f * mu1 * mu2 + C1) / (mu1 * mu1 + mu2 * mu2 + C1)) * cv;
  }
  float t = blockSum256(sv);
  if (threadIdx.x == 0) atomicAdd(acc + SSIM_SLOT(scale, 0, img), t);
  t = blockSum256(cv);
  if (threadIdx.x == 0) atomicAdd(acc + SSIM_SLOT(scale, 1, img), t);
}

__global__ __launch_bounds__(256) void down2_k(const float* __restrict__ X,
                                               float* __restrict__ O, int n) {
  const int h = n >> 1;
  const int total = 6 * h * h;
  const int idx = blockIdx.x * 256 + threadIdx.x;
  if (idx >= total) return;
  const int img = idx / (h * h);
  const int rem = idx - img * (h * h);
  const int r = rem / h, cl = rem - r * h;
  const float* xb = X + (size_t)img * n * n + (size_t)(2 * r) * n + 2 * cl;
  O[idx] = 0.25f * (xb[0] + xb[1] + xb[n] + xb[n + 1]);
}

// ---------------- VGG ----------------

// merged weight transform: all 6 MFMA layers in one launch.
struct WTArgs {
  const float* w[6];
  int co[6], ci[6];
  int cum[7];           // cumulative element offsets into dst
};
__global__ __launch_bounds__(256) void wt_transform_all(WTArgs a, unsigned short* __restrict__ dst) {
  const int idx = blockIdx.x * 256 + threadIdx.x;
  if (idx >= a.cum[6]) return;
  int L = 0;
  while (idx >= a.cum[L + 1]) ++L;
  const int r = idx - a.cum[L];
  const int Cin = a.ci[L];
  const int cin = r % Cin;
  const int t = r / Cin;
  const int tap = t % 9;
  const int cout = t / 9;
  dst[idx] = f2bf(a.w[L][((size_t)cout * Cin + cin) * 9 + tap]);
}

// zero the 1-px border of a padded NHWC buffer (H+2, W+2, C)
__global__ __launch_bounds__(256) void zero_border(unsigned short* __restrict__ buf,
                                                   int H, int W, int C) {
  const int Wp = W + 2;
  const int rowE = Wp * C;
  const int total = 2 * rowE + 2 * H * C;
  const int idx = blockIdx.x * 256 + threadIdx.x;
  if (idx >= total) return;
  size_t o;
  if (idx < rowE) o = idx;
  else if (idx < 2 * rowE) o = (size_t)(H + 1) * rowE + (idx - rowE);
  else {
    const int k = idx - 2 * rowE;
    const int y = k / (2 * C) + 1;
    const int r = k % (2 * C);
    const int x = (r < C) ? 0 : (W + 1);
    const int c = (r < C) ? r : (r - C);
    o = (size_t)y * rowE + (size_t)x * C + c;
  }
  buf[o] = 0;
}

// layer1: Cin=3 direct conv, NCHW fp32 in -> padded NHWC bf16 out (Cout=64)
__global__ __launch_bounds__(256) void conv1_k(
    const float* __restrict__ in, const float* __restrict__ wt,
    const float* __restrict__ bias, unsigned short* __restrict__ out, int HW) {
  __shared__ float sIn[3][10][12];
  const int tx = threadIdx.x, ty = threadIdx.y, tz = threadIdx.z;
  const int tid = (tz << 6) | (ty << 3) | tx;
  const int x0 = blockIdx.x << 3, y0 = blockIdx.y << 3;
  const int x = x0 + tx, y = y0 + ty;
  int wrow = (blockIdx.z * 16 + tz * 4) * 27;
  wrow = __builtin_amdgcn_readfirstlane(wrow);

  for (int el = tid; el < 300; el += 256) {
    const int ci = el / 100;
    const int rem = el - ci * 100;
    const int r = rem / 10, cl = rem - r * 10;
    const int gy = y0 - 1 + r, gx = x0 - 1 + cl;
    float v = 0.f;
    if (gy >= 0 && gy < HW && gx >= 0 && gx < HW)
      v = in[((size_t)ci * HW + gy) * HW + gx];
    sIn[ci][r][cl] = v;
  }
  __syncthreads();

  float a0 = 0.f, a1 = 0.f, a2 = 0.f, a3 = 0.f;
#pragma unroll
  for (int ci = 0; ci < 3; ++ci) {
    float xv[9];
#pragma unroll
    for (int ky = 0; ky < 3; ++ky)
#pragma unroll
      for (int kx = 0; kx < 3; ++kx)
        xv[ky * 3 + kx] = sIn[ci][ty + ky][tx + kx];
    const float* wp = wt + wrow + ci * 9;
#pragma unroll
    for (int k = 0; k < 9; ++k) {
      a0 = fmaf(xv[k], wp[k], a0);
      a1 = fmaf(xv[k], wp[27 + k], a1);
      a2 = fmaf(xv[k], wp[54 + k], a2);
      a3 = fmaf(xv[k], wp[81 + k], a3);
    }
  }
  const int coB = blockIdx.z * 16 + tz * 4;
  const size_t o = ((size_t)(y + 1) * (HW + 2) + (x + 1)) * 64 + coB;
  uint2 pk;
  pk.x = (unsigned int)f2bf(fmaxf(a0 + bias[coB + 0], 0.f)) |
         ((unsigned int)f2bf(fmaxf(a1 + bias[coB + 1], 0.f)) << 16);
  pk.y = (unsigned int)f2bf(fmaxf(a2 + bias[coB + 2], 0.f)) |
         ((unsigned int)f2bf(fmaxf(a3 + bias[coB + 3], 0.f)) << 16);
  *(uint2*)(out + o) = pk;
}

// implicit-GEMM conv3x3 SAME + bias + relu via mfma_f32_16x16x32_bf16.
template<int CIN, int WTM, int WTN>
__global__ __launch_bounds__(256) void conv_mfma(
    const unsigned short* __restrict__ in, const unsigned short* __restrict__ wtp,
    const float* __restrict__ bias, unsigned short* __restrict__ out,
    int W, int Cout) {
  const int tid = threadIdx.x;
  const int lane = tid & 63;
  const int wave = tid >> 6;
  const int quad = lane >> 4;
  const int lr = lane & 15;
  const int wc = wave & 1;
  const int wp = wave >> 1;
  const int y = blockIdx.y;
  const int Wp = W + 2;
  const int xw = blockIdx.x * (WTN * 32) + wp * (WTN * 16);
  const int cob = blockIdx.z * (WTM * 32) + wc * (WTM * 16);

  floatx4 acc[WTM][WTN];
#pragma unroll
  for (int m = 0; m < WTM; ++m)
#pragma unroll
    for (int n = 0; n < WTN; ++n) acc[m][n] = (floatx4){0.f, 0.f, 0.f, 0.f};

  const unsigned short* aln[WTM];
#pragma unroll
  for (int m = 0; m < WTM; ++m)
    aln[m] = wtp + (size_t)(cob + m * 16 + lr) * (9 * CIN) + quad * 8;
  const unsigned short* bbase = in + ((size_t)y * Wp + xw + lr) * CIN + quad * 8;

#pragma unroll
  for (int tap = 0; tap < 9; ++tap) {
    const int dy = tap / 3, dx = tap - dy * 3;
    const unsigned short* bt = bbase + (dy * Wp + dx) * CIN;
#pragma unroll
    for (int c0 = 0; c0 < CIN / 32; ++c0) {
      short8 af[WTM], bfr[WTN];
#pragma unroll
      for (int m = 0; m < WTM; ++m)
        af[m] = *(const short8*)(aln[m] + tap * CIN + c0 * 32);
#pragma unroll
      for (int n = 0; n < WTN; ++n)
        bfr[n] = *(const short8*)(bt + n * 16 * CIN + c0 * 32);
#pragma unroll
      for (int m = 0; m < WTM; ++m)
#pragma unroll
        for (int n = 0; n < WTN; ++n)
          acc[m][n] = __builtin_amdgcn_mfma_f32_16x16x32_bf16(af[m], bfr[n], acc[m][n], 0, 0, 0);
    }
  }

#pragma unroll
  for (int m = 0; m < WTM; ++m) {
    const int cb = cob + m * 16 + quad * 4;
#pragma unroll
    for (int n = 0; n < WTN; ++n) {
      const int px = xw + n * 16 + lr;
      if (px < W) {
        const float v0 = fmaxf(acc[m][n].x + bias[cb + 0], 0.f);
        const float v1 = fmaxf(acc[m][n].y + bias[cb + 1], 0.f);
        const float v2 = fmaxf(acc[m][n].z + bias[cb + 2], 0.f);
        const float v3 = fmaxf(acc[m][n].w + bias[cb + 3], 0.f);
        uint2 pk;
        pk.x = (unsigned int)f2bf(v0) | ((unsigned int)f2bf(v1) << 16);
        pk.y = (unsigned int)f2bf(v2) | ((unsigned int)f2bf(v3) << 16);
        *(uint2*)(out + ((size_t)(y + 1) * Wp + px + 1) * Cout + cb) = pk;
      }
    }
  }
}

// 2x2 maxpool on padded NHWC bf16: (2Ho+2,2Wo+2,C) -> interior of (Ho+2,Wo+2,C)
__global__ __launch_bounds__(256) void pool_nhwc(const unsigned short* __restrict__ in,
                                                 unsigned short* __restrict__ out,
                                                 int Ho, int Wo, int C) {
  const int total = Ho * Wo * C;
  const int idx = blockIdx.x * 256 + threadIdx.x;
  if (idx >= total) return;
  const int c = idx % C;
  const int p = idx / C;
  const int x = p % Wo, y = p / Wo;
  const int Wi = 2 * Wo + 2;
  const unsigned short* ib = in + ((size_t)(2 * y + 1) * Wi + (2 * x + 1)) * C + c;
  const float a = bf2f(ib[0]), b = bf2f(ib[C]);
  const float d = bf2f(ib[(size_t)Wi * C]), e = bf2f(ib[(size_t)Wi * C + C]);
  out[((size_t)(y + 1) * (Wo + 2) + x + 1) * C + c] = f2bf(fmaxf(fmaxf(a, b), fmaxf(d, e)));
}

// perceptual: grid-stride, 8 bf16/load, few atomics
typedef __attribute__((ext_vector_type(8))) unsigned short ushort8;
__global__ __launch_bounds__(256) void perc_k(const unsigned short* __restrict__ f1,
                                              const unsigned short* __restrict__ f2,
                                              float* __restrict__ acc) {
  const int NCHUNK = 56 * 56 * 256 / 8;   // 100352
  float v = 0.f;
  for (int ch = blockIdx.x * 256 + threadIdx.x; ch < NCHUNK; ch += 128 * 256) {
    const int e = ch * 8;
    const int c = e & 255;
    const int p = e >> 8;
    const int x = p % 56, y = p / 56;
    const size_t o = ((size_t)(y + 1) * 58 + x + 1) * 256 + c;
    const ushort8 a = *(const ushort8*)(f1 + o);
    const ushort8 b = *(const ushort8*)(f2 + o);
#pragma unroll
    for (int j = 0; j < 8; ++j) {
      const float d = bf2f(a[j]) - bf2f(b[j]);
      v = fmaf(d, d, v);
    }
  }
  const float t = blockSum256(v);
  if (threadIdx.x == 0) atomicAdd(acc + SLOT(ACC_PERC), t);
}

// ---------------- final combine ----------------
__global__ void final_k(const float* __restrict__ acc, float* __restrict__ out) {
  if (threadIdx.x != 0 || blockIdx.x != 0) return;
  const float NPIX = 2.f * 3.f * 224.f * 224.f;
  const float l1 = acc[SLOT(ACC_L1)] / NPIX;
  const float mse = acc[SLOT(ACC_MSE)] / NPIX;
  const float psnr = 40.f + 10.f * log10f(mse);
  const float cm = 1.f / (3.f * 224.f * 224.f);
  const float color = 0.5f * (fabsf(acc[SLOT(ACC_ST0)] - acc[SLOT(ACC_SP0)]) +
                              fabsf(acc[SLOT(ACC_ST1)] - acc[SLOT(ACC_SP1)])) * cm;
  const float ill = acc[SLOT(ACC_HV)] / 669.f + acc[SLOT(ACC_WV)] / 448.f;
  const float expl = acc[SLOT(ACC_EXP)] / 392.f;
  const float spat = acc[SLOT(ACC_SPAT)] / 6272.f;
  const float perc = acc[SLOT(ACC_PERC)] / 1605632.f;
  const float wms[5] = {0.0448f, 0.2856f, 0.3001f, 0.2363f, 0.1333f};
  const int ns[5] = {214, 102, 46, 18, 4};
  float msum = 0.f;
  for (int img = 0; img < 6; ++img) {
    float prod = 1.f;
    for (int s = 0; s < 5; ++s) {
      const float denom = (float)(ns[s] * ns[s]);
      float v = (s == 4) ? acc[SSIM_SLOT(s, 0, img)] / denom
                         : acc[SSIM_SLOT(s, 1, img)] / denom;
      v = fmaxf(v, 0.f);
      prod *= powf(v, wms[s]);
    }
    msum += prod;
  }
  const float msssim = msum / 6.f;
  out[0] = l1 + 0.06f * perc + 0.0083f * psnr + 0.25f * color +
           0.5f * (1.f - msssim) + 0.1f * expl + 0.1f * ill + 0.1f * spat;
}

extern "C" void kernel_launch(void* const* d_in, const int* in_sizes, int n_in,
                              void* d_out, int out_size, void* d_ws, size_t ws_size,
                              hipStream_t stream) {
  const float* yt = (const float*)d_in[0];
  const float* yp = (const float*)d_in[1];
  const float* W7[7]; const float* B7[7];
  for (int i = 0; i < 7; ++i) {
    W7[i] = (const float*)d_in[2 + 2 * i];
    B7[i] = (const float*)d_in[3 + 2 * i];
  }

  // Dedicated per-geometry buffers => borders zeroed ONCE per call, never corrupted.
  char* ws = (char*)d_ws;
  float* acc = (float*)ws;
  size_t off = 16384;
  float* op = (float*)(ws + off); off += 2 * 3136 * 4;
  float* ep = (float*)(ws + off); off += 2 * 3136 * 4;
  auto align256 = [&]() { off = (off + 255) & ~(size_t)255; };
  align256(); unsigned short* C1  = (unsigned short*)(ws + off); off += (size_t)226 * 226 * 64 * 2;   // L1 out (border)
  align256(); unsigned short* T0  = (unsigned short*)(ws + off); off += (size_t)226 * 226 * 64 * 2;   // C2/C4/L7pred (no border)
  align256(); unsigned short* Pl1 = (unsigned short*)(ws + off); off += (size_t)114 * 114 * 64 * 2;   // pool1 (border)
  align256(); unsigned short* C3  = (unsigned short*)(ws + off); off += (size_t)114 * 114 * 128 * 2;  // L3 out (border)
  align256(); unsigned short* Pl2 = (unsigned short*)(ws + off); off += (size_t)58 * 58 * 128 * 2;    // pool2 (border)
  align256(); unsigned short* C5  = (unsigned short*)(ws + off); off += (size_t)58 * 58 * 256 * 2;    // L5 out (border)
  align256(); unsigned short* C6  = (unsigned short*)(ws + off); off += (size_t)58 * 58 * 256 * 2;    // L6 out (border)
  align256(); unsigned short* F   = (unsigned short*)(ws + off); off += (size_t)58 * 58 * 256 * 2;    // L7 y_true out
  align256(); unsigned short* WT  = (unsigned short*)(ws + off); off += (size_t)1732608 * 2;
  if (ws_size < off) return;

  // pre-VGG scratch aliases (T0/F need no preserved state before VGG)
  float* tmp5 = (float*)T0;            // 5.76 MB needed, T0 = 6.54 MB
  float* pyrX = (float*)F;             // 0.8 MB in F (1.72 MB)
  float* pyrY = (float*)F + 100000;

  GW gw;
  {
    double vv[11]; double s = 0.0;
    for (int i = 0; i < 11; ++i) { const double c = i - 5.0; vv[i] = exp(-(c * c) / 4.5); s += vv[i]; }
    for (int i = 0; i < 11; ++i) gw.g[i] = (float)(vv[i] / s);
  }

  hipMemsetAsync(acc, 0, 16384, stream);

  // merged weight transform (one launch)
  const int co[7] = {64, 64, 128, 128, 256, 256, 256};
  const int ci[7] = {3, 64, 64, 128, 128, 256, 256};
  WTArgs wa;
  size_t wtOff[7];
  {
    int e = 0;
    for (int i = 1; i < 7; ++i) {
      wa.w[i - 1] = W7[i]; wa.co[i - 1] = co[i]; wa.ci[i - 1] = ci[i];
      wa.cum[i - 1] = e; wtOff[i] = (size_t)e; e += co[i] * 9 * ci[i];
    }
    wa.cum[6] = e;
  }
  wt_transform_all<<<(wa.cum[6] + 255) / 256, 256, 0, stream>>>(wa, WT);

  // borders: once per call (buffers are geometry-dedicated)
  auto zb = [&](unsigned short* buf, int HW, int C) {
    const int tot = 2 * (HW + 2) * C + 2 * HW * C;
    zero_border<<<(tot + 255) / 256, 256, 0, stream>>>(buf, HW, HW, C);
  };
  zb(C1, 224, 64); zb(Pl1, 112, 64); zb(C3, 112, 128);
  zb(Pl2, 56, 128); zb(C5, 56, 256); zb(C6, 56, 256);

  basic_stats<<<256, 256, 0, stream>>>(yt, yp, acc);
  exposure_k<<<392, 256, 0, stream>>>(yp, acc);
  pool4_lum_k<<<25, 256, 0, stream>>>(yt, yp, op, ep);
  spat_k<<<25, 256, 0, stream>>>(op, ep, acc);

  // MS-SSIM over 5 scales (scratch in T0/F, strictly before VGG)
  const int dims[5] = {224, 112, 56, 28, 14};
  const int pyrOff[4] = {0, 75264, 94080, 98784};
  const float* Xs = yt; const float* Ys = yp;
  for (int s = 0; s < 5; ++s) {
    const int n = dims[s], m = n - 10;
    const int totV = 6 * m * n;
    gaussV_k<<<(totV + 255) / 256, 256, 0, stream>>>(Xs, Ys, tmp5, n, gw);
    dim3 gh((m * m + 255) / 256, 6);
    gaussH_ssim_k<<<gh, 256, 0, stream>>>(tmp5, acc, n, s, gw);
    if (s < 4) {
      const int hn = n >> 1;
      const int totD = 6 * hn * hn;
      float* nx = pyrX + pyrOff[s];
      float* ny = pyrY + pyrOff[s];
      down2_k<<<(totD + 255) / 256, 256, 0, stream>>>(Xs, nx, n);
      down2_k<<<(totD + 255) / 256, 256, 0, stream>>>(Ys, ny, n);
      Xs = nx; Ys = ny;
    }
  }

  // VGG19[:16] on 4 images (2 batch x {y_true, y_pred})
  for (int b = 0; b < 2; ++b) {
    for (int pass = 0; pass < 2; ++pass) {
      const float* src = (pass == 0 ? yt : yp) + (size_t)b * 3 * 224 * 224;
      conv1_k<<<dim3(28, 28, 4), dim3(8, 8, 4), 0, stream>>>(src, W7[0], B7[0], C1, 224);
      conv_mfma<64, 2, 2><<<dim3(4, 224, 1), 256, 0, stream>>>(C1, WT + wtOff[1], B7[1], T0, 224, 64);
      pool_nhwc<<<(112 * 112 * 64 + 255) / 256, 256, 0, stream>>>(T0, Pl1, 112, 112, 64);
      conv_mfma<64, 2, 2><<<dim3(2, 112, 2), 256, 0, stream>>>(Pl1, WT + wtOff[2], B7[2], C3, 112, 128);
      conv_mfma<128, 2, 2><<<dim3(2, 112, 2), 256, 0, stream>>>(C3, WT + wtOff[3], B7[3], T0, 112, 128);
      pool_nhwc<<<(56 * 56 * 128 + 255) / 256, 256, 0, stream>>>(T0, Pl2, 56, 56, 128);
      conv_mfma<128, 2, 1><<<dim3(2, 56, 4), 256, 0, stream>>>(Pl2, WT + wtOff[4], B7[4], C5, 56, 256);
      conv_mfma<256, 2, 1><<<dim3(2, 56, 4), 256, 0, stream>>>(C5, WT + wtOff[5], B7[5], C6, 56, 256);
      unsigned short* dst = (pass == 0) ? F : T0;
      conv_mfma<256, 2, 1><<<dim3(2, 56, 4), 256, 0, stream>>>(C6, WT + wtOff[6], B7[6], dst, 56, 256);
    }
    perc_k<<<128, 256, 0, stream>>>(F, T0, acc);
  }

  final_k<<<1, 64, 0, stream>>>(acc, (float*)d_out);
}

// Round 4
// 1086.659 us; speedup vs baseline: 3.2356x; 1.0266x over previous
//
#include <hip/hip_runtime.h>
#include <cmath>

typedef __attribute__((ext_vector_type(8))) short  short8;
typedef __attribute__((ext_vector_type(4))) float  floatx4;
typedef __attribute__((ext_vector_type(8))) unsigned short ushort8;

// Accumulator slots spread 64B apart to avoid same-cacheline atomic serialization.
#define SLOT(i) ((i) * 16)
#define ACC_L1   0
#define ACC_MSE  1
#define ACC_ST0  2
#define ACC_ST1  3
#define ACC_SP0  4
#define ACC_SP1  5
#define ACC_HV   6
#define ACC_WV   7
#define ACC_EXP  8
#define ACC_SPAT 9
#define ACC_PERC 10
#define SSIM_SLOT(scale, cs, img) (256 + ((scale) * 12 + (cs) * 6 + (img)) * 16)

struct GW { float g[11]; };

__device__ __forceinline__ float waveSum(float v) {
#pragma unroll
  for (int o = 32; o > 0; o >>= 1) v += __shfl_down(v, o, 64);
  return v;
}

__device__ __forceinline__ float blockSum256(float v) {
  __shared__ float red[4];
  const int tid = threadIdx.x;
  v = waveSum(v);
  __syncthreads();
  if ((tid & 63) == 0) red[tid >> 6] = v;
  __syncthreads();
  return red[0] + red[1] + red[2] + red[3];
}

__device__ __forceinline__ unsigned short f2bf(float f) {
  union { float f; unsigned int u; } v; v.f = f;
  const unsigned int u = v.u;
  return (unsigned short)((u + 0x7fffu + ((u >> 16) & 1u)) >> 16);
}
__device__ __forceinline__ float bf2f(unsigned short h) {
  union { unsigned int u; float f; } v; v.u = ((unsigned int)h) << 16;
  return v.f;
}

// ---------------- small loss terms ----------------

__global__ __launch_bounds__(256) void basic_stats(const float* __restrict__ yt,
                                                   const float* __restrict__ yp,
                                                   float* __restrict__ acc) {
  const int N = 2 * 3 * 224 * 224;
  float l1 = 0.f, mse = 0.f, st0 = 0.f, st1 = 0.f, sp0 = 0.f, sp1 = 0.f, hv = 0.f, wv = 0.f;
  for (int idx = blockIdx.x * 256 + threadIdx.x; idx < N; idx += 256 * 256) {
    const float t = yt[idx], p = yp[idx];
    const float d = p - t;
    const float ad = fabsf(d);
    l1 += (ad < 1.f) ? 0.5f * d * d : ad - 0.5f;
    mse += d * d;
    if (idx < 3 * 224 * 224) { st0 += t; sp0 += p; } else { st1 += t; sp1 += p; }
    const int w = idx % 224;
    const int h = (idx / 224) % 224;
    if (h < 223) { const float dv = yp[idx + 224] - p; hv += dv * dv; }
    if (w < 223) { const float dw = yp[idx + 1] - p; wv += dw * dw; }
  }
  float s;
  s = blockSum256(l1);  if (threadIdx.x == 0) atomicAdd(acc + SLOT(ACC_L1), s);
  s = blockSum256(mse); if (threadIdx.x == 0) atomicAdd(acc + SLOT(ACC_MSE), s);
  s = blockSum256(st0); if (threadIdx.x == 0) atomicAdd(acc + SLOT(ACC_ST0), s);
  s = blockSum256(st1); if (threadIdx.x == 0) atomicAdd(acc + SLOT(ACC_ST1), s);
  s = blockSum256(sp0); if (threadIdx.x == 0) atomicAdd(acc + SLOT(ACC_SP0), s);
  s = blockSum256(sp1); if (threadIdx.x == 0) atomicAdd(acc + SLOT(ACC_SP1), s);
  s = blockSum256(hv);  if (threadIdx.x == 0) atomicAdd(acc + SLOT(ACC_HV), s);
  s = blockSum256(wv);  if (threadIdx.x == 0) atomicAdd(acc + SLOT(ACC_WV), s);
}

__global__ __launch_bounds__(256) void exposure_k(const float* __restrict__ yp,
                                                  float* __restrict__ acc) {
  const int blk = blockIdx.x;
  const int b = blk / 196;
  const int rem = blk - b * 196;
  const int py = rem / 14, px = rem - py * 14;
  float s = 0.f;
  for (int e = threadIdx.x; e < 768; e += 256) {
    const int c = e >> 8;
    const int rr = (e >> 4) & 15;
    const int cc = e & 15;
    s += yp[(((size_t)b * 3 + c) * 224 + py * 16 + rr) * 224 + px * 16 + cc];
  }
  const float t = blockSum256(s);
  if (threadIdx.x == 0) {
    const float m = t * (1.f / 768.f) - 0.6f;
    atomicAdd(acc + SLOT(ACC_EXP), m * m);
  }
}

__global__ __launch_bounds__(256) void pool4_lum_k(const float* __restrict__ yt,
                                                   const float* __restrict__ yp,
                                                   float* __restrict__ op,
                                                   float* __restrict__ ep) {
  const int idx = blockIdx.x * 256 + threadIdx.x;
  if (idx >= 2 * 56 * 56) return;
  const int b = idx / 3136;
  const int rem = idx - b * 3136;
  const int r = rem / 56, cl = rem - r * 56;
  float so = 0.f, se = 0.f;
  for (int c = 0; c < 3; ++c)
    for (int dy = 0; dy < 4; ++dy)
      for (int dx = 0; dx < 4; ++dx) {
        const size_t off = (((size_t)b * 3 + c) * 224 + (r * 4 + dy)) * 224 + cl * 4 + dx;
        so += yt[off]; se += yp[off];
      }
  op[idx] = so * (1.f / 48.f);
  ep[idx] = se * (1.f / 48.f);
}

__global__ __launch_bounds__(256) void spat_k(const float* __restrict__ op,
                                              const float* __restrict__ ep,
                                              float* __restrict__ acc) {
  const int idx = blockIdx.x * 256 + threadIdx.x;
  float v = 0.f;
  if (idx < 6272) {
    const int rem = idx % 3136;
    const int r = rem / 56, cl = rem - r * 56;
    const float oc = op[idx], ec = ep[idx];
    const float ol = (cl > 0)  ? op[idx - 1]  : 0.f;
    const float el = (cl > 0)  ? ep[idx - 1]  : 0.f;
    const float orr = (cl < 55) ? op[idx + 1]  : 0.f;
    const float er  = (cl < 55) ? ep[idx + 1]  : 0.f;
    const float ou = (r > 0)   ? op[idx - 56] : 0.f;
    const float eu = (r > 0)   ? ep[idx - 56] : 0.f;
    const float od = (r < 55)  ? op[idx + 56] : 0.f;
    const float ed = (r < 55)  ? ep[idx + 56] : 0.f;
    float d;
    d = (oc - ol) - (ec - el);   v += d * d;
    d = (oc - orr) - (ec - er);  v += d * d;
    d = (oc - ou) - (ec - eu);   v += d * d;
    d = (oc - od) - (ec - ed);   v += d * d;
  }
  const float t = blockSum256(v);
  if (threadIdx.x == 0) atomicAdd(acc + SLOT(ACC_SPAT), t);
}

// ---------------- MS-SSIM ----------------

__global__ __launch_bounds__(256) void gaussV_k(const float* __restrict__ X,
                                                const float* __restrict__ Y,
                                                float* __restrict__ tmp, int n, GW gw) {
  const int m = n - 10;
  const int total = 6 * m * n;
  const int idx = blockIdx.x * 256 + threadIdx.x;
  if (idx >= total) return;
  const int img = idx / (m * n);
  const int rem = idx - img * (m * n);
  const int r = rem / n, cl = rem - r * n;
  const float* xb = X + (size_t)img * n * n + (size_t)r * n + cl;
  const float* yb = Y + (size_t)img * n * n + (size_t)r * n + cl;
  float sx = 0.f, sy = 0.f, sxx = 0.f, syy = 0.f, sxy = 0.f;
#pragma unroll
  for (int t = 0; t < 11; ++t) {
    const float xv = xb[(size_t)t * n];
    const float yv = yb[(size_t)t * n];
    const float g = gw.g[t];
    sx += g * xv; sy += g * yv;
    sxx += g * xv * xv; syy += g * yv * yv; sxy += g * xv * yv;
  }
  const size_t st = (size_t)6 * m * n;
  tmp[idx] = sx; tmp[st + idx] = sy;
  tmp[2 * st + idx] = sxx; tmp[3 * st + idx] = syy; tmp[4 * st + idx] = sxy;
}

__global__ __launch_bounds__(256) void gaussH_ssim_k(const float* __restrict__ tmp,
                                                     float* __restrict__ acc,
                                                     int n, int scale, GW gw) {
  const int m = n - 10;
  const int img = blockIdx.y;
  const int pid = blockIdx.x * 256 + threadIdx.x;
  float sv = 0.f, cv = 0.f;
  if (pid < m * m) {
    const int r = pid / m, cl = pid - r * m;
    const size_t st = (size_t)6 * m * n;
    const float* t0 = tmp + (size_t)img * m * n + (size_t)r * n + cl;
    float mu1 = 0.f, mu2 = 0.f, e11 = 0.f, e22 = 0.f, e12 = 0.f;
#pragma unroll
    for (int t = 0; t < 11; ++t) {
      const float g = gw.g[t];
      mu1 += g * t0[t];
      mu2 += g * t0[st + t];
      e11 += g * t0[2 * st + t];
      e22 += g * t0[3 * st + t];
      e12 += g * t0[4 * st + t];
    }
    const float C1 = 1e-4f, C2 = 9e-4f;
    const float s11 = e11 - mu1 * mu1;
    const float s22 = e22 - mu2 * mu2;
    const float s12 = e12 - mu1 * mu2;
    cv = (2.f * s12 + C2) / (s11 + s22 + C2);
    sv = ((2.f * mu1 * mu2 + C1) / (mu1 * mu1 + mu2 * mu2 + C1)) * cv;
  }
  float t = blockSum256(sv);
  if (threadIdx.x == 0) atomicAdd(acc + SSIM_SLOT(scale, 0, img), t);
  t = blockSum256(cv);
  if (threadIdx.x == 0) atomicAdd(acc + SSIM_SLOT(scale, 1, img), t);
}

__global__ __launch_bounds__(256) void down2_k(const float* __restrict__ X,
                                               float* __restrict__ O, int n) {
  const int h = n >> 1;
  const int total = 6 * h * h;
  const int idx = blockIdx.x * 256 + threadIdx.x;
  if (idx >= total) return;
  const int img = idx / (h * h);
  const int rem = idx - img * (h * h);
  const int r = rem / h, cl = rem - r * h;
  const float* xb = X + (size_t)img * n * n + (size_t)(2 * r) * n + 2 * cl;
  O[idx] = 0.25f * (xb[0] + xb[1] + xb[n] + xb[n + 1]);
}

// ---------------- VGG ----------------

struct WTArgs {
  const float* w[6];
  int co[6], ci[6];
  int cum[7];
};
__global__ __launch_bounds__(256) void wt_transform_all(WTArgs a, unsigned short* __restrict__ dst) {
  const int idx = blockIdx.x * 256 + threadIdx.x;
  if (idx >= a.cum[6]) return;
  int L = 0;
  while (idx >= a.cum[L + 1]) ++L;
  const int r = idx - a.cum[L];
  const int Cin = a.ci[L];
  const int cin = r % Cin;
  const int t = r / Cin;
  const int tap = t % 9;
  const int cout = t / 9;
  dst[idx] = f2bf(a.w[L][((size_t)cout * Cin + cin) * 9 + tap]);
}

__global__ __launch_bounds__(256) void zero_border(unsigned short* __restrict__ buf,
                                                   int H, int W, int C) {
  const int Wp = W + 2;
  const int rowE = Wp * C;
  const int total = 2 * rowE + 2 * H * C;
  const int idx = blockIdx.x * 256 + threadIdx.x;
  if (idx >= total) return;
  size_t o;
  if (idx < rowE) o = idx;
  else if (idx < 2 * rowE) o = (size_t)(H + 1) * rowE + (idx - rowE);
  else {
    const int k = idx - 2 * rowE;
    const int y = k / (2 * C) + 1;
    const int r = k % (2 * C);
    const int x = (r < C) ? 0 : (W + 1);
    const int c = (r < C) ? r : (r - C);
    o = (size_t)y * rowE + (size_t)x * C + c;
  }
  buf[o] = 0;
}

// layer1: Cin=3 direct conv, NCHW fp32 in -> padded NHWC bf16 out (Cout=64)
__global__ __launch_bounds__(256) void conv1_k(
    const float* __restrict__ in, const float* __restrict__ wt,
    const float* __restrict__ bias, unsigned short* __restrict__ out, int HW) {
  __shared__ float sIn[3][10][12];
  const int tx = threadIdx.x, ty = threadIdx.y, tz = threadIdx.z;
  const int tid = (tz << 6) | (ty << 3) | tx;
  const int x0 = blockIdx.x << 3, y0 = blockIdx.y << 3;
  const int x = x0 + tx, y = y0 + ty;
  int wrow = (blockIdx.z * 16 + tz * 4) * 27;
  wrow = __builtin_amdgcn_readfirstlane(wrow);

  for (int el = tid; el < 300; el += 256) {
    const int ci = el / 100;
    const int rem = el - ci * 100;
    const int r = rem / 10, cl = rem - r * 10;
    const int gy = y0 - 1 + r, gx = x0 - 1 + cl;
    float v = 0.f;
    if (gy >= 0 && gy < HW && gx >= 0 && gx < HW)
      v = in[((size_t)ci * HW + gy) * HW + gx];
    sIn[ci][r][cl] = v;
  }
  __syncthreads();

  float a0 = 0.f, a1 = 0.f, a2 = 0.f, a3 = 0.f;
#pragma unroll
  for (int ci = 0; ci < 3; ++ci) {
    float xv[9];
#pragma unroll
    for (int ky = 0; ky < 3; ++ky)
#pragma unroll
      for (int kx = 0; kx < 3; ++kx)
        xv[ky * 3 + kx] = sIn[ci][ty + ky][tx + kx];
    const float* wp = wt + wrow + ci * 9;
#pragma unroll
    for (int k = 0; k < 9; ++k) {
      a0 = fmaf(xv[k], wp[k], a0);
      a1 = fmaf(xv[k], wp[27 + k], a1);
      a2 = fmaf(xv[k], wp[54 + k], a2);
      a3 = fmaf(xv[k], wp[81 + k], a3);
    }
  }
  const int coB = blockIdx.z * 16 + tz * 4;
  const size_t o = ((size_t)(y + 1) * (HW + 2) + (x + 1)) * 64 + coB;
  uint2 pk;
  pk.x = (unsigned int)f2bf(fmaxf(a0 + bias[coB + 0], 0.f)) |
         ((unsigned int)f2bf(fmaxf(a1 + bias[coB + 1], 0.f)) << 16);
  pk.y = (unsigned int)f2bf(fmaxf(a2 + bias[coB + 2], 0.f)) |
         ((unsigned int)f2bf(fmaxf(a3 + bias[coB + 3], 0.f)) << 16);
  *(uint2*)(out + o) = pk;
}

// implicit-GEMM conv3x3 via mfma_f32_16x16x32_bf16 with explicit software pipeline.
// Wave tile: (WTM*16 cout) x (WTN*16 px) x ROWS output rows. Block = 4 waves (wc=2, wp=2).
// K-loop flattened to chunks of 32 cin; PF chunks of A/B fragments prefetched in
// register ring buffers so PF*(WTM+ROWS*WTN) loads stay in flight (AITER-style
// vmcnt!=0 pipelining at source level).
// NOTE: B-loads for guarded-out px may overread a few KB past this buffer's tail
// into the NEXT ws buffer (never past d_ws); those columns are discarded by the
// px<W store guard (MFMA columns are independent).
template<int CIN, int WTM, int WTN, int ROWS, int PF>
__global__ __launch_bounds__(256, 4) void conv_mfma(
    const unsigned short* __restrict__ in, const unsigned short* __restrict__ wtp,
    const float* __restrict__ bias, unsigned short* __restrict__ out,
    int W, int Cout) {
  constexpr int NCH = 9 * (CIN / 32);
  constexpr int NBUF = PF + 1;
  const int lane = threadIdx.x & 63;
  const int wave = threadIdx.x >> 6;
  const int quad = lane >> 4;
  const int lr = lane & 15;
  const int wc = wave & 1;
  const int wp = wave >> 1;
  const int y0 = blockIdx.y * ROWS;
  const int Wp = W + 2;
  const int xw = blockIdx.x * (WTN * 32) + wp * (WTN * 16);
  const int cob = blockIdx.z * (WTM * 32) + wc * (WTM * 16);

  floatx4 acc[ROWS][WTM][WTN];
#pragma unroll
  for (int r = 0; r < ROWS; ++r)
#pragma unroll
    for (int m = 0; m < WTM; ++m)
#pragma unroll
      for (int n = 0; n < WTN; ++n) acc[r][m][n] = (floatx4){0.f, 0.f, 0.f, 0.f};

  const unsigned short* aptr[WTM];
#pragma unroll
  for (int m = 0; m < WTM; ++m)
    aptr[m] = wtp + (size_t)(cob + m * 16 + lr) * (9 * CIN) + quad * 8;
  const unsigned short* bb[ROWS];
#pragma unroll
  for (int r = 0; r < ROWS; ++r)
    bb[r] = in + ((size_t)(y0 + r) * Wp + xw + lr) * CIN + quad * 8;

  short8 Af[NBUF][WTM];
  short8 Bf[NBUF][ROWS][WTN];

  auto loadChunk = [&](int kk, int p) {
    const int tap = kk / (CIN / 32);
    const int c0 = kk - tap * (CIN / 32);
    const int dy = tap / 3, dx = tap - dy * 3;
    const int boff = (dy * Wp + dx) * CIN + c0 * 32;
#pragma unroll
    for (int m = 0; m < WTM; ++m)
      Af[p][m] = *(const short8*)(aptr[m] + kk * 32);
#pragma unroll
    for (int r = 0; r < ROWS; ++r)
#pragma unroll
      for (int n = 0; n < WTN; ++n)
        Bf[p][r][n] = *(const short8*)(bb[r] + n * 16 * CIN + boff);
  };

#pragma unroll
  for (int i = 0; i < PF; ++i) loadChunk(i, i % NBUF);

#pragma unroll
  for (int kk = 0; kk < NCH; ++kk) {
    if (kk + PF < NCH) loadChunk(kk + PF, (kk + PF) % NBUF);
    const int p = kk % NBUF;
#pragma unroll
    for (int r = 0; r < ROWS; ++r)
#pragma unroll
      for (int m = 0; m < WTM; ++m)
#pragma unroll
        for (int n = 0; n < WTN; ++n)
          acc[r][m][n] = __builtin_amdgcn_mfma_f32_16x16x32_bf16(Af[p][m], Bf[p][r][n], acc[r][m][n], 0, 0, 0);
  }

#pragma unroll
  for (int r = 0; r < ROWS; ++r)
#pragma unroll
    for (int m = 0; m < WTM; ++m) {
      const int cb = cob + m * 16 + quad * 4;
#pragma unroll
      for (int n = 0; n < WTN; ++n) {
        const int px = xw + n * 16 + lr;
        if (px < W) {
          const float v0 = fmaxf(acc[r][m][n].x + bias[cb + 0], 0.f);
          const float v1 = fmaxf(acc[r][m][n].y + bias[cb + 1], 0.f);
          const float v2 = fmaxf(acc[r][m][n].z + bias[cb + 2], 0.f);
          const float v3 = fmaxf(acc[r][m][n].w + bias[cb + 3], 0.f);
          uint2 pk;
          pk.x = (unsigned int)f2bf(v0) | ((unsigned int)f2bf(v1) << 16);
          pk.y = (unsigned int)f2bf(v2) | ((unsigned int)f2bf(v3) << 16);
          *(uint2*)(out + ((size_t)(y0 + r + 1) * Wp + px + 1) * Cout + cb) = pk;
        }
      }
    }
}

__global__ __launch_bounds__(256) void pool_nhwc(const unsigned short* __restrict__ in,
                                                 unsigned short* __restrict__ out,
                                                 int Ho, int Wo, int C) {
  const int total = Ho * Wo * C;
  const int idx = blockIdx.x * 256 + threadIdx.x;
  if (idx >= total) return;
  const int c = idx % C;
  const int p = idx / C;
  const int x = p % Wo, y = p / Wo;
  const int Wi = 2 * Wo + 2;
  const unsigned short* ib = in + ((size_t)(2 * y + 1) * Wi + (2 * x + 1)) * C + c;
  const float a = bf2f(ib[0]), b = bf2f(ib[C]);
  const float d = bf2f(ib[(size_t)Wi * C]), e = bf2f(ib[(size_t)Wi * C + C]);
  out[((size_t)(y + 1) * (Wo + 2) + x + 1) * C + c] = f2bf(fmaxf(fmaxf(a, b), fmaxf(d, e)));
}

__global__ __launch_bounds__(256) void perc_k(const unsigned short* __restrict__ f1,
                                              const unsigned short* __restrict__ f2,
                                              float* __restrict__ acc) {
  const int NCHUNK = 56 * 56 * 256 / 8;
  float v = 0.f;
  for (int ch = blockIdx.x * 256 + threadIdx.x; ch < NCHUNK; ch += 128 * 256) {
    const int e = ch * 8;
    const int c = e & 255;
    const int p = e >> 8;
    const int x = p % 56, y = p / 56;
    const size_t o = ((size_t)(y + 1) * 58 + x + 1) * 256 + c;
    const ushort8 a = *(const ushort8*)(f1 + o);
    const ushort8 b = *(const ushort8*)(f2 + o);
#pragma unroll
    for (int j = 0; j < 8; ++j) {
      const float d = bf2f(a[j]) - bf2f(b[j]);
      v = fmaf(d, d, v);
    }
  }
  const float t = blockSum256(v);
  if (threadIdx.x == 0) atomicAdd(acc + SLOT(ACC_PERC), t);
}

// ---------------- final combine ----------------
__global__ void final_k(const float* __restrict__ acc, float* __restrict__ out) {
  if (threadIdx.x != 0 || blockIdx.x != 0) return;
  const float NPIX = 2.f * 3.f * 224.f * 224.f;
  const float l1 = acc[SLOT(ACC_L1)] / NPIX;
  const float mse = acc[SLOT(ACC_MSE)] / NPIX;
  const float psnr = 40.f + 10.f * log10f(mse);
  const float cm = 1.f / (3.f * 224.f * 224.f);
  const float color = 0.5f * (fabsf(acc[SLOT(ACC_ST0)] - acc[SLOT(ACC_SP0)]) +
                              fabsf(acc[SLOT(ACC_ST1)] - acc[SLOT(ACC_SP1)])) * cm;
  const float ill = acc[SLOT(ACC_HV)] / 669.f + acc[SLOT(ACC_WV)] / 448.f;
  const float expl = acc[SLOT(ACC_EXP)] / 392.f;
  const float spat = acc[SLOT(ACC_SPAT)] / 6272.f;
  const float perc = acc[SLOT(ACC_PERC)] / 1605632.f;
  const float wms[5] = {0.0448f, 0.2856f, 0.3001f, 0.2363f, 0.1333f};
  const int ns[5] = {214, 102, 46, 18, 4};
  float msum = 0.f;
  for (int img = 0; img < 6; ++img) {
    float prod = 1.f;
    for (int s = 0; s < 5; ++s) {
      const float denom = (float)(ns[s] * ns[s]);
      float v = (s == 4) ? acc[SSIM_SLOT(s, 0, img)] / denom
                         : acc[SSIM_SLOT(s, 1, img)] / denom;
      v = fmaxf(v, 0.f);
      prod *= powf(v, wms[s]);
    }
    msum += prod;
  }
  const float msssim = msum / 6.f;
  out[0] = l1 + 0.06f * perc + 0.0083f * psnr + 0.25f * color +
           0.5f * (1.f - msssim) + 0.1f * expl + 0.1f * ill + 0.1f * spat;
}

extern "C" void kernel_launch(void* const* d_in, const int* in_sizes, int n_in,
                              void* d_out, int out_size, void* d_ws, size_t ws_size,
                              hipStream_t stream) {
  const float* yt = (const float*)d_in[0];
  const float* yp = (const float*)d_in[1];
  const float* W7[7]; const float* B7[7];
  for (int i = 0; i < 7; ++i) {
    W7[i] = (const float*)d_in[2 + 2 * i];
    B7[i] = (const float*)d_in[3 + 2 * i];
  }

  char* ws = (char*)d_ws;
  float* acc = (float*)ws;
  size_t off = 16384;
  float* op = (float*)(ws + off); off += 2 * 3136 * 4;
  float* ep = (float*)(ws + off); off += 2 * 3136 * 4;
  auto align256 = [&]() { off = (off + 255) & ~(size_t)255; };
  align256(); unsigned short* C1  = (unsigned short*)(ws + off); off += (size_t)226 * 226 * 64 * 2;
  align256(); unsigned short* T0  = (unsigned short*)(ws + off); off += (size_t)226 * 226 * 64 * 2;
  align256(); unsigned short* Pl1 = (unsigned short*)(ws + off); off += (size_t)114 * 114 * 64 * 2;
  align256(); unsigned short* C3  = (unsigned short*)(ws + off); off += (size_t)114 * 114 * 128 * 2;
  align256(); unsigned short* Pl2 = (unsigned short*)(ws + off); off += (size_t)58 * 58 * 128 * 2;
  align256(); unsigned short* C5  = (unsigned short*)(ws + off); off += (size_t)58 * 58 * 256 * 2;
  align256(); unsigned short* C6  = (unsigned short*)(ws + off); off += (size_t)58 * 58 * 256 * 2;
  align256(); unsigned short* F   = (unsigned short*)(ws + off); off += (size_t)58 * 58 * 256 * 2;
  align256(); unsigned short* WT  = (unsigned short*)(ws + off); off += (size_t)1732608 * 2;
  if (ws_size < off) return;

  float* tmp5 = (float*)T0;
  float* pyrX = (float*)F;
  float* pyrY = (float*)F + 100000;

  GW gw;
  {
    double vv[11]; double s = 0.0;
    for (int i = 0; i < 11; ++i) { const double c = i - 5.0; vv[i] = exp(-(c * c) / 4.5); s += vv[i]; }
    for (int i = 0; i < 11; ++i) gw.g[i] = (float)(vv[i] / s);
  }

  hipMemsetAsync(acc, 0, 16384, stream);

  const int co[7] = {64, 64, 128, 128, 256, 256, 256};
  const int ci[7] = {3, 64, 64, 128, 128, 256, 256};
  WTArgs wa;
  size_t wtOff[7];
  {
    int e = 0;
    for (int i = 1; i < 7; ++i) {
      wa.w[i - 1] = W7[i]; wa.co[i - 1] = co[i]; wa.ci[i - 1] = ci[i];
      wa.cum[i - 1] = e; wtOff[i] = (size_t)e; e += co[i] * 9 * ci[i];
    }
    wa.cum[6] = e;
  }
  wt_transform_all<<<(wa.cum[6] + 255) / 256, 256, 0, stream>>>(wa, WT);

  auto zb = [&](unsigned short* buf, int HW, int C) {
    const int tot = 2 * (HW + 2) * C + 2 * HW * C;
    zero_border<<<(tot + 255) / 256, 256, 0, stream>>>(buf, HW, HW, C);
  };
  zb(C1, 224, 64); zb(Pl1, 112, 64); zb(C3, 112, 128);
  zb(Pl2, 56, 128); zb(C5, 56, 256); zb(C6, 56, 256);

  basic_stats<<<256, 256, 0, stream>>>(yt, yp, acc);
  exposure_k<<<392, 256, 0, stream>>>(yp, acc);
  pool4_lum_k<<<25, 256, 0, stream>>>(yt, yp, op, ep);
  spat_k<<<25, 256, 0, stream>>>(op, ep, acc);

  const int dims[5] = {224, 112, 56, 28, 14};
  const int pyrOff[4] = {0, 75264, 94080, 98784};
  const float* Xs = yt; const float* Ys = yp;
  for (int s = 0; s < 5; ++s) {
    const int n = dims[s], m = n - 10;
    const int totV = 6 * m * n;
    gaussV_k<<<(totV + 255) / 256, 256, 0, stream>>>(Xs, Ys, tmp5, n, gw);
    dim3 gh((m * m + 255) / 256, 6);
    gaussH_ssim_k<<<gh, 256, 0, stream>>>(tmp5, acc, n, s, gw);
    if (s < 4) {
      const int hn = n >> 1;
      const int totD = 6 * hn * hn;
      float* nx = pyrX + pyrOff[s];
      float* ny = pyrY + pyrOff[s];
      down2_k<<<(totD + 255) / 256, 256, 0, stream>>>(Xs, nx, n);
      down2_k<<<(totD + 255) / 256, 256, 0, stream>>>(Ys, ny, n);
      Xs = nx; Ys = ny;
    }
  }

  // VGG19[:16] on 4 images. conv_mfma<CIN, WTM, WTN, ROWS, PF>, 448 blocks each.
  for (int b = 0; b < 2; ++b) {
    for (int pass = 0; pass < 2; ++pass) {
      const float* src = (pass == 0 ? yt : yp) + (size_t)b * 3 * 224 * 224;
      conv1_k<<<dim3(28, 28, 4), dim3(8, 8, 4), 0, stream>>>(src, W7[0], B7[0], C1, 224);
      conv_mfma<64, 2, 2, 2, 1><<<dim3(4, 112, 1), 256, 0, stream>>>(C1, WT + wtOff[1], B7[1], T0, 224, 64);
      pool_nhwc<<<(112 * 112 * 64 + 255) / 256, 256, 0, stream>>>(T0, Pl1, 112, 112, 64);
      conv_mfma<64, 2, 1, 2, 2><<<dim3(4, 56, 2), 256, 0, stream>>>(Pl1, WT + wtOff[2], B7[2], C3, 112, 128);
      conv_mfma<128, 2, 1, 2, 2><<<dim3(4, 56, 2), 256, 0, stream>>>(C3, WT + wtOff[3], B7[3], T0, 112, 128);
      pool_nhwc<<<(56 * 56 * 128 + 255) / 256, 256, 0, stream>>>(T0, Pl2, 56, 56, 128);
      conv_mfma<128, 2, 1, 1, 2><<<dim3(2, 56, 4), 256, 0, stream>>>(Pl2, WT + wtOff[4], B7[4], C5, 56, 256);
      conv_mfma<256, 2, 1, 1, 2><<<dim3(2, 56, 4), 256, 0, stream>>>(C5, WT + wtOff[5], B7[5], C6, 56, 256);
      unsigned short* dst = (pass == 0) ? F : T0;
      conv_mfma<256, 2, 1, 1, 2><<<dim3(2, 56, 4), 256, 0, stream>>>(C6, WT + wtOff[6], B7[6], dst, 56, 256);
    }
    perc_k<<<128, 256, 0, stream>>>(F, T0, acc);
  }

  final_k<<<1, 64, 0, stream>>>(acc, (float*)d_out);
}

// Round 5
// 617.822 us; speedup vs baseline: 5.6909x; 1.7589x over previous
//
#include <hip/hip_runtime.h>
#include <cmath>

typedef __attribute__((ext_vector_type(8))) short  short8;
typedef __attribute__((ext_vector_type(4))) float  floatx4;
typedef __attribute__((ext_vector_type(8))) unsigned short ushort8;

// Accumulator slots spread 64B apart to avoid same-cacheline atomic serialization.
#define SLOT(i) ((i) * 16)
#define ACC_L1   0
#define ACC_MSE  1
#define ACC_ST0  2
#define ACC_ST1  3
#define ACC_SP0  4
#define ACC_SP1  5
#define ACC_HV   6
#define ACC_WV   7
#define ACC_EXP  8
#define ACC_SPAT 9
#define ACC_PERC 10
#define SSIM_SLOT(scale, cs, img) (256 + ((scale) * 12 + (cs) * 6 + (img)) * 16)

struct GW { float g[11]; };

__device__ __forceinline__ float waveSum(float v) {
#pragma unroll
  for (int o = 32; o > 0; o >>= 1) v += __shfl_down(v, o, 64);
  return v;
}

__device__ __forceinline__ float blockSum256(float v) {
  __shared__ float red[4];
  const int tid = threadIdx.x;
  v = waveSum(v);
  __syncthreads();
  if ((tid & 63) == 0) red[tid >> 6] = v;
  __syncthreads();
  return red[0] + red[1] + red[2] + red[3];
}

__device__ __forceinline__ unsigned short f2bf(float f) {
  union { float f; unsigned int u; } v; v.f = f;
  const unsigned int u = v.u;
  return (unsigned short)((u + 0x7fffu + ((u >> 16) & 1u)) >> 16);
}
__device__ __forceinline__ float bf2f(unsigned short h) {
  union { unsigned int u; float f; } v; v.u = ((unsigned int)h) << 16;
  return v.f;
}

// ---------------- small loss terms ----------------

__global__ __launch_bounds__(256) void basic_stats(const float* __restrict__ yt,
                                                   const float* __restrict__ yp,
                                                   float* __restrict__ acc) {
  const int N = 2 * 3 * 224 * 224;
  float l1 = 0.f, mse = 0.f, st0 = 0.f, st1 = 0.f, sp0 = 0.f, sp1 = 0.f, hv = 0.f, wv = 0.f;
  for (int idx = blockIdx.x * 256 + threadIdx.x; idx < N; idx += 256 * 256) {
    const float t = yt[idx], p = yp[idx];
    const float d = p - t;
    const float ad = fabsf(d);
    l1 += (ad < 1.f) ? 0.5f * d * d : ad - 0.5f;
    mse += d * d;
    if (idx < 3 * 224 * 224) { st0 += t; sp0 += p; } else { st1 += t; sp1 += p; }
    const int w = idx % 224;
    const int h = (idx / 224) % 224;
    if (h < 223) { const float dv = yp[idx + 224] - p; hv += dv * dv; }
    if (w < 223) { const float dw = yp[idx + 1] - p; wv += dw * dw; }
  }
  float s;
  s = blockSum256(l1);  if (threadIdx.x == 0) atomicAdd(acc + SLOT(ACC_L1), s);
  s = blockSum256(mse); if (threadIdx.x == 0) atomicAdd(acc + SLOT(ACC_MSE), s);
  s = blockSum256(st0); if (threadIdx.x == 0) atomicAdd(acc + SLOT(ACC_ST0), s);
  s = blockSum256(st1); if (threadIdx.x == 0) atomicAdd(acc + SLOT(ACC_ST1), s);
  s = blockSum256(sp0); if (threadIdx.x == 0) atomicAdd(acc + SLOT(ACC_SP0), s);
  s = blockSum256(sp1); if (threadIdx.x == 0) atomicAdd(acc + SLOT(ACC_SP1), s);
  s = blockSum256(hv);  if (threadIdx.x == 0) atomicAdd(acc + SLOT(ACC_HV), s);
  s = blockSum256(wv);  if (threadIdx.x == 0) atomicAdd(acc + SLOT(ACC_WV), s);
}

__global__ __launch_bounds__(256) void exposure_k(const float* __restrict__ yp,
                                                  float* __restrict__ acc) {
  const int blk = blockIdx.x;
  const int b = blk / 196;
  const int rem = blk - b * 196;
  const int py = rem / 14, px = rem - py * 14;
  float s = 0.f;
  for (int e = threadIdx.x; e < 768; e += 256) {
    const int c = e >> 8;
    const int rr = (e >> 4) & 15;
    const int cc = e & 15;
    s += yp[(((size_t)b * 3 + c) * 224 + py * 16 + rr) * 224 + px * 16 + cc];
  }
  const float t = blockSum256(s);
  if (threadIdx.x == 0) {
    const float m = t * (1.f / 768.f) - 0.6f;
    atomicAdd(acc + SLOT(ACC_EXP), m * m);
  }
}

__global__ __launch_bounds__(256) void pool4_lum_k(const float* __restrict__ yt,
                                                   const float* __restrict__ yp,
                                                   float* __restrict__ op,
                                                   float* __restrict__ ep) {
  const int idx = blockIdx.x * 256 + threadIdx.x;
  if (idx >= 2 * 56 * 56) return;
  const int b = idx / 3136;
  const int rem = idx - b * 3136;
  const int r = rem / 56, cl = rem - r * 56;
  float so = 0.f, se = 0.f;
  for (int c = 0; c < 3; ++c)
    for (int dy = 0; dy < 4; ++dy)
      for (int dx = 0; dx < 4; ++dx) {
        const size_t off = (((size_t)b * 3 + c) * 224 + (r * 4 + dy)) * 224 + cl * 4 + dx;
        so += yt[off]; se += yp[off];
      }
  op[idx] = so * (1.f / 48.f);
  ep[idx] = se * (1.f / 48.f);
}

__global__ __launch_bounds__(256) void spat_k(const float* __restrict__ op,
                                              const float* __restrict__ ep,
                                              float* __restrict__ acc) {
  const int idx = blockIdx.x * 256 + threadIdx.x;
  float v = 0.f;
  if (idx < 6272) {
    const int rem = idx % 3136;
    const int r = rem / 56, cl = rem - r * 56;
    const float oc = op[idx], ec = ep[idx];
    const float ol = (cl > 0)  ? op[idx - 1]  : 0.f;
    const float el = (cl > 0)  ? ep[idx - 1]  : 0.f;
    const float orr = (cl < 55) ? op[idx + 1]  : 0.f;
    const float er  = (cl < 55) ? ep[idx + 1]  : 0.f;
    const float ou = (r > 0)   ? op[idx - 56] : 0.f;
    const float eu = (r > 0)   ? ep[idx - 56] : 0.f;
    const float od = (r < 55)  ? op[idx + 56] : 0.f;
    const float ed = (r < 55)  ? ep[idx + 56] : 0.f;
    float d;
    d = (oc - ol) - (ec - el);   v += d * d;
    d = (oc - orr) - (ec - er);  v += d * d;
    d = (oc - ou) - (ec - eu);   v += d * d;
    d = (oc - od) - (ec - ed);   v += d * d;
  }
  const float t = blockSum256(v);
  if (threadIdx.x == 0) atomicAdd(acc + SLOT(ACC_SPAT), t);
}

// ---------------- MS-SSIM ----------------

__global__ __launch_bounds__(256) void gaussV_k(const float* __restrict__ X,
                                                const float* __restrict__ Y,
                                                float* __restrict__ tmp, int n, GW gw) {
  const int m = n - 10;
  const int total = 6 * m * n;
  const int idx = blockIdx.x * 256 + threadIdx.x;
  if (idx >= total) return;
  const int img = idx / (m * n);
  const int rem = idx - img * (m * n);
  const int r = rem / n, cl = rem - r * n;
  const float* xb = X + (size_t)img * n * n + (size_t)r * n + cl;
  const float* yb = Y + (size_t)img * n * n + (size_t)r * n + cl;
  float sx = 0.f, sy = 0.f, sxx = 0.f, syy = 0.f, sxy = 0.f;
#pragma unroll
  for (int t = 0; t < 11; ++t) {
    const float xv = xb[(size_t)t * n];
    const float yv = yb[(size_t)t * n];
    const float g = gw.g[t];
    sx += g * xv; sy += g * yv;
    sxx += g * xv * xv; syy += g * yv * yv; sxy += g * xv * yv;
  }
  const size_t st = (size_t)6 * m * n;
  tmp[idx] = sx; tmp[st + idx] = sy;
  tmp[2 * st + idx] = sxx; tmp[3 * st + idx] = syy; tmp[4 * st + idx] = sxy;
}

__global__ __launch_bounds__(256) void gaussH_ssim_k(const float* __restrict__ tmp,
                                                     float* __restrict__ acc,
                                                     int n, int scale, GW gw) {
  const int m = n - 10;
  const int img = blockIdx.y;
  const int pid = blockIdx.x * 256 + threadIdx.x;
  float sv = 0.f, cv = 0.f;
  if (pid < m * m) {
    const int r = pid / m, cl = pid - r * m;
    const size_t st = (size_t)6 * m * n;
    const float* t0 = tmp + (size_t)img * m * n + (size_t)r * n + cl;
    float mu1 = 0.f, mu2 = 0.f, e11 = 0.f, e22 = 0.f, e12 = 0.f;
#pragma unroll
    for (int t = 0; t < 11; ++t) {
      const float g = gw.g[t];
      mu1 += g * t0[t];
      mu2 += g * t0[st + t];
      e11 += g * t0[2 * st + t];
      e22 += g * t0[3 * st + t];
      e12 += g * t0[4 * st + t];
    }
    const float C1 = 1e-4f, C2 = 9e-4f;
    const float s11 = e11 - mu1 * mu1;
    const float s22 = e22 - mu2 * mu2;
    const float s12 = e12 - mu1 * mu2;
    cv = (2.f * s12 + C2) / (s11 + s22 + C2);
    sv = ((2.f * mu1 * mu2 + C1) / (mu1 * mu1 + mu2 * mu2 + C1)) * cv;
  }
  float t = blockSum256(sv);
  if (threadIdx.x == 0) atomicAdd(acc + SSIM_SLOT(scale, 0, img), t);
  t = blockSum256(cv);
  if (threadIdx.x == 0) atomicAdd(acc + SSIM_SLOT(scale, 1, img), t);
}

__global__ __launch_bounds__(256) void down2_k(const float* __restrict__ X,
                                               float* __restrict__ O, int n) {
  const int h = n >> 1;
  const int total = 6 * h * h;
  const int idx = blockIdx.x * 256 + threadIdx.x;
  if (idx >= total) return;
  const int img = idx / (h * h);
  const int rem = idx - img * (h * h);
  const int r = rem / h, cl = rem - r * h;
  const float* xb = X + (size_t)img * n * n + (size_t)(2 * r) * n + 2 * cl;
  O[idx] = 0.25f * (xb[0] + xb[1] + xb[n] + xb[n + 1]);
}

// ---------------- VGG ----------------

struct WTArgs {
  const float* w[6];
  int co[6], ci[6];
  int cum[7];
};
__global__ __launch_bounds__(256) void wt_transform_all(WTArgs a, unsigned short* __restrict__ dst) {
  const int idx = blockIdx.x * 256 + threadIdx.x;
  if (idx >= a.cum[6]) return;
  int L = 0;
  while (idx >= a.cum[L + 1]) ++L;
  const int r = idx - a.cum[L];
  const int Cin = a.ci[L];
  const int cin = r % Cin;
  const int t = r / Cin;
  const int tap = t % 9;
  const int cout = t / 9;
  dst[idx] = f2bf(a.w[L][((size_t)cout * Cin + cin) * 9 + tap]);
}

__global__ __launch_bounds__(256) void zero_border(unsigned short* __restrict__ buf,
                                                   int H, int W, int C) {
  const int Wp = W + 2;
  const int rowE = Wp * C;
  const int total = 2 * rowE + 2 * H * C;
  const int idx = blockIdx.x * 256 + threadIdx.x;
  if (idx >= total) return;
  size_t o;
  if (idx < rowE) o = idx;
  else if (idx < 2 * rowE) o = (size_t)(H + 1) * rowE + (idx - rowE);
  else {
    const int k = idx - 2 * rowE;
    const int y = k / (2 * C) + 1;
    const int r = k % (2 * C);
    const int x = (r < C) ? 0 : (W + 1);
    const int c = (r < C) ? r : (r - C);
    o = (size_t)y * rowE + (size_t)x * C + c;
  }
  buf[o] = 0;
}

// layer1: Cin=3 direct conv, NCHW fp32 in -> padded NHWC bf16 out (Cout=64)
__global__ __launch_bounds__(256) void conv1_k(
    const float* __restrict__ in, const float* __restrict__ wt,
    const float* __restrict__ bias, unsigned short* __restrict__ out, int HW) {
  __shared__ float sIn[3][10][12];
  const int tx = threadIdx.x, ty = threadIdx.y, tz = threadIdx.z;
  const int tid = (tz << 6) | (ty << 3) | tx;
  const int x0 = blockIdx.x << 3, y0 = blockIdx.y << 3;
  const int x = x0 + tx, y = y0 + ty;
  int wrow = (blockIdx.z * 16 + tz * 4) * 27;
  wrow = __builtin_amdgcn_readfirstlane(wrow);

  for (int el = tid; el < 300; el += 256) {
    const int ci = el / 100;
    const int rem = el - ci * 100;
    const int r = rem / 10, cl = rem - r * 10;
    const int gy = y0 - 1 + r, gx = x0 - 1 + cl;
    float v = 0.f;
    if (gy >= 0 && gy < HW && gx >= 0 && gx < HW)
      v = in[((size_t)ci * HW + gy) * HW + gx];
    sIn[ci][r][cl] = v;
  }
  __syncthreads();

  float a0 = 0.f, a1 = 0.f, a2 = 0.f, a3 = 0.f;
#pragma unroll
  for (int ci = 0; ci < 3; ++ci) {
    float xv[9];
#pragma unroll
    for (int ky = 0; ky < 3; ++ky)
#pragma unroll
      for (int kx = 0; kx < 3; ++kx)
        xv[ky * 3 + kx] = sIn[ci][ty + ky][tx + kx];
    const float* wp = wt + wrow + ci * 9;
#pragma unroll
    for (int k = 0; k < 9; ++k) {
      a0 = fmaf(xv[k], wp[k], a0);
      a1 = fmaf(xv[k], wp[27 + k], a1);
      a2 = fmaf(xv[k], wp[54 + k], a2);
      a3 = fmaf(xv[k], wp[81 + k], a3);
    }
  }
  const int coB = blockIdx.z * 16 + tz * 4;
  const size_t o = ((size_t)(y + 1) * (HW + 2) + (x + 1)) * 64 + coB;
  uint2 pk;
  pk.x = (unsigned int)f2bf(fmaxf(a0 + bias[coB + 0], 0.f)) |
         ((unsigned int)f2bf(fmaxf(a1 + bias[coB + 1], 0.f)) << 16);
  pk.y = (unsigned int)f2bf(fmaxf(a2 + bias[coB + 2], 0.f)) |
         ((unsigned int)f2bf(fmaxf(a3 + bias[coB + 3], 0.f)) << 16);
  *(uint2*)(out + o) = pk;
}

// implicit-GEMM conv3x3 via mfma_f32_16x16x32_bf16 — m97-style barrier-anchored
// LDS staging (register-ring pipelining is un-anchorable at source: the scheduler
// sinks loads; measured R4 VGPR=24/32, MfmaUtil 3%).
// Per cin-slab (32ch): stage W-tile (64co x 9tap x 32ci) + input patch
// ((TY+2) x 66px x 32ci) into LDS with bulk 16B loads (MLP ~14/thread, drained
// once at the barrier), then a pure ds_read_b128+MFMA tap loop.
// LDS strides 296/40 elem: dword-stride ≡ 4·odd (mod 32) -> every 8 lanes of a
// b128 read tile all 32 banks (conflict-free) and stay 16B-aligned.
// Block: 4 waves (2co x 2px), block tile 64co x 64px x TY rows.
template<int CIN, int TY>
__global__ __launch_bounds__(256, 2) void conv_mfma(
    const unsigned short* __restrict__ in, const unsigned short* __restrict__ wtp,
    const float* __restrict__ bias, unsigned short* __restrict__ out,
    int W, int Cout) {
  constexpr int NSLAB = CIN / 32;
  constexpr int AST = 296;                 // A cout-stride (288+8)
  constexpr int BST = 40;                  // B px-stride (32+8)
  constexpr int NBRUN = (TY + 2) * 66;     // B patch px-runs
  constexpr int NBCH = NBRUN * 4;          // 16B chunks in B patch
  __shared__ unsigned short As[64 * AST];
  __shared__ unsigned short Bs[NBRUN * BST];

  const int tid = threadIdx.x;
  const int lane = tid & 63;
  const int wave = tid >> 6;
  const int quad = lane >> 4;
  const int lr = lane & 15;
  const int wc = wave & 1;
  const int wp = wave >> 1;
  const int y0 = blockIdx.y * TY;
  const int x0 = blockIdx.x * 64;
  const int cob = blockIdx.z * 64;
  const int Wp = W + 2;

  floatx4 acc[TY][2][2];
#pragma unroll
  for (int r = 0; r < TY; ++r)
#pragma unroll
    for (int m = 0; m < 2; ++m)
#pragma unroll
      for (int n = 0; n < 2; ++n) acc[r][m][n] = (floatx4){0.f, 0.f, 0.f, 0.f};

  const int abase = (wc * 32 + lr) * AST + quad * 8;   // + m*16*AST + tap*32
  const int bbase = (wp * 32 + lr) * BST + quad * 8;   // + n*16*BST + ((r+dy)*66+dx)*BST

  for (int s = 0; s < NSLAB; ++s) {
    __syncthreads();
    // stage A: 64co x 9tap x 32ci = 2304 16B-chunks = 9/thread
#pragma unroll
    for (int i = 0; i < 9; ++i) {
      const int ee = tid + i * 256;
      const int cout = ee / 36;
      const int rem = ee - cout * 36;
      const int tap = rem >> 2;
      const int part = rem & 3;
      const short8 v = *(const short8*)(wtp + ((size_t)(cob + cout) * 9 + tap) * CIN + s * 32 + part * 8);
      *(short8*)(As + cout * AST + tap * 32 + part * 8) = v;
    }
    // stage B patch: (TY+2) rows x 66 px x 32 ci
#pragma unroll
    for (int i = 0; i < (NBCH + 255) / 256; ++i) {
      const int ee = tid + i * 256;
      if (ee < NBCH) {
        const int part = ee & 3;
        const int run = ee >> 2;
        const int row = run / 66;
        const int px = run - row * 66;
        short8 v = {0, 0, 0, 0, 0, 0, 0, 0};
        const int gx = x0 + px;
        if (gx < Wp)
          v = *(const short8*)(in + ((size_t)(y0 + row) * Wp + gx) * CIN + s * 32 + part * 8);
        *(short8*)(Bs + run * BST + part * 8) = v;
      }
    }
    __syncthreads();

    // compute: 9 taps, pure LDS + MFMA
#pragma unroll
    for (int dy = 0; dy < 3; ++dy)
#pragma unroll
      for (int dx = 0; dx < 3; ++dx) {
        const int tap = dy * 3 + dx;
        const short8 af0 = *(const short8*)(As + abase + tap * 32);
        const short8 af1 = *(const short8*)(As + abase + 16 * AST + tap * 32);
        short8 bfr[TY][2];
#pragma unroll
        for (int r = 0; r < TY; ++r)
#pragma unroll
          for (int n = 0; n < 2; ++n)
            bfr[r][n] = *(const short8*)(Bs + bbase + n * 16 * BST + ((r + dy) * 66 + dx) * BST);
#pragma unroll
        for (int r = 0; r < TY; ++r)
#pragma unroll
          for (int n = 0; n < 2; ++n) {
            acc[r][0][n] = __builtin_amdgcn_mfma_f32_16x16x32_bf16(af0, bfr[r][n], acc[r][0][n], 0, 0, 0);
            acc[r][1][n] = __builtin_amdgcn_mfma_f32_16x16x32_bf16(af1, bfr[r][n], acc[r][1][n], 0, 0, 0);
          }
      }
  }

#pragma unroll
  for (int r = 0; r < TY; ++r)
#pragma unroll
    for (int m = 0; m < 2; ++m) {
      const int cb = cob + wc * 32 + m * 16 + quad * 4;
#pragma unroll
      for (int n = 0; n < 2; ++n) {
        const int px = x0 + wp * 32 + n * 16 + lr;
        if (px < W) {
          const float v0 = fmaxf(acc[r][m][n].x + bias[cb + 0], 0.f);
          const float v1 = fmaxf(acc[r][m][n].y + bias[cb + 1], 0.f);
          const float v2 = fmaxf(acc[r][m][n].z + bias[cb + 2], 0.f);
          const float v3 = fmaxf(acc[r][m][n].w + bias[cb + 3], 0.f);
          uint2 pk;
          pk.x = (unsigned int)f2bf(v0) | ((unsigned int)f2bf(v1) << 16);
          pk.y = (unsigned int)f2bf(v2) | ((unsigned int)f2bf(v3) << 16);
          *(uint2*)(out + ((size_t)(y0 + r + 1) * Wp + px + 1) * Cout + cb) = pk;
        }
      }
    }
}

__global__ __launch_bounds__(256) void pool_nhwc(const unsigned short* __restrict__ in,
                                                 unsigned short* __restrict__ out,
                                                 int Ho, int Wo, int C) {
  const int total = Ho * Wo * C;
  const int idx = blockIdx.x * 256 + threadIdx.x;
  if (idx >= total) return;
  const int c = idx % C;
  const int p = idx / C;
  const int x = p % Wo, y = p / Wo;
  const int Wi = 2 * Wo + 2;
  const unsigned short* ib = in + ((size_t)(2 * y + 1) * Wi + (2 * x + 1)) * C + c;
  const float a = bf2f(ib[0]), b = bf2f(ib[C]);
  const float d = bf2f(ib[(size_t)Wi * C]), e = bf2f(ib[(size_t)Wi * C + C]);
  out[((size_t)(y + 1) * (Wo + 2) + x + 1) * C + c] = f2bf(fmaxf(fmaxf(a, b), fmaxf(d, e)));
}

__global__ __launch_bounds__(256) void perc_k(const unsigned short* __restrict__ f1,
                                              const unsigned short* __restrict__ f2,
                                              float* __restrict__ acc) {
  const int NCHUNK = 56 * 56 * 256 / 8;
  float v = 0.f;
  for (int ch = blockIdx.x * 256 + threadIdx.x; ch < NCHUNK; ch += 128 * 256) {
    const int e = ch * 8;
    const int c = e & 255;
    const int p = e >> 8;
    const int x = p % 56, y = p / 56;
    const size_t o = ((size_t)(y + 1) * 58 + x + 1) * 256 + c;
    const ushort8 a = *(const ushort8*)(f1 + o);
    const ushort8 b = *(const ushort8*)(f2 + o);
#pragma unroll
    for (int j = 0; j < 8; ++j) {
      const float d = bf2f(a[j]) - bf2f(b[j]);
      v = fmaf(d, d, v);
    }
  }
  const float t = blockSum256(v);
  if (threadIdx.x == 0) atomicAdd(acc + SLOT(ACC_PERC), t);
}

// ---------------- final combine ----------------
__global__ void final_k(const float* __restrict__ acc, float* __restrict__ out) {
  if (threadIdx.x != 0 || blockIdx.x != 0) return;
  const float NPIX = 2.f * 3.f * 224.f * 224.f;
  const float l1 = acc[SLOT(ACC_L1)] / NPIX;
  const float mse = acc[SLOT(ACC_MSE)] / NPIX;
  const float psnr = 40.f + 10.f * log10f(mse);
  const float cm = 1.f / (3.f * 224.f * 224.f);
  const float color = 0.5f * (fabsf(acc[SLOT(ACC_ST0)] - acc[SLOT(ACC_SP0)]) +
                              fabsf(acc[SLOT(ACC_ST1)] - acc[SLOT(ACC_SP1)])) * cm;
  const float ill = acc[SLOT(ACC_HV)] / 669.f + acc[SLOT(ACC_WV)] / 448.f;
  const float expl = acc[SLOT(ACC_EXP)] / 392.f;
  const float spat = acc[SLOT(ACC_SPAT)] / 6272.f;
  const float perc = acc[SLOT(ACC_PERC)] / 1605632.f;
  const float wms[5] = {0.0448f, 0.2856f, 0.3001f, 0.2363f, 0.1333f};
  const int ns[5] = {214, 102, 46, 18, 4};
  float msum = 0.f;
  for (int img = 0; img < 6; ++img) {
    float prod = 1.f;
    for (int s = 0; s < 5; ++s) {
      const float denom = (float)(ns[s] * ns[s]);
      float v = (s == 4) ? acc[SSIM_SLOT(s, 0, img)] / denom
                         : acc[SSIM_SLOT(s, 1, img)] / denom;
      v = fmaxf(v, 0.f);
      prod *= powf(v, wms[s]);
    }
    msum += prod;
  }
  const float msssim = msum / 6.f;
  out[0] = l1 + 0.06f * perc + 0.0083f * psnr + 0.25f * color +
           0.5f * (1.f - msssim) + 0.1f * expl + 0.1f * ill + 0.1f * spat;
}

extern "C" void kernel_launch(void* const* d_in, const int* in_sizes, int n_in,
                              void* d_out, int out_size, void* d_ws, size_t ws_size,
                              hipStream_t stream) {
  const float* yt = (const float*)d_in[0];
  const float* yp = (const float*)d_in[1];
  const float* W7[7]; const float* B7[7];
  for (int i = 0; i < 7; ++i) {
    W7[i] = (const float*)d_in[2 + 2 * i];
    B7[i] = (const float*)d_in[3 + 2 * i];
  }

  char* ws = (char*)d_ws;
  float* acc = (float*)ws;
  size_t off = 16384;
  float* op = (float*)(ws + off); off += 2 * 3136 * 4;
  float* ep = (float*)(ws + off); off += 2 * 3136 * 4;
  auto align256 = [&]() { off = (off + 255) & ~(size_t)255; };
  align256(); unsigned short* C1  = (unsigned short*)(ws + off); off += (size_t)226 * 226 * 64 * 2;
  align256(); unsigned short* T0  = (unsigned short*)(ws + off); off += (size_t)226 * 226 * 64 * 2;
  align256(); unsigned short* Pl1 = (unsigned short*)(ws + off); off += (size_t)114 * 114 * 64 * 2;
  align256(); unsigned short* C3  = (unsigned short*)(ws + off); off += (size_t)114 * 114 * 128 * 2;
  align256(); unsigned short* Pl2 = (unsigned short*)(ws + off); off += (size_t)58 * 58 * 128 * 2;
  align256(); unsigned short* C5  = (unsigned short*)(ws + off); off += (size_t)58 * 58 * 256 * 2;
  align256(); unsigned short* C6  = (unsigned short*)(ws + off); off += (size_t)58 * 58 * 256 * 2;
  align256(); unsigned short* F   = (unsigned short*)(ws + off); off += (size_t)58 * 58 * 256 * 2;
  align256(); unsigned short* WT  = (unsigned short*)(ws + off); off += (size_t)1732608 * 2;
  if (ws_size < off) return;

  float* tmp5 = (float*)T0;
  float* pyrX = (float*)F;
  float* pyrY = (float*)F + 100000;

  GW gw;
  {
    double vv[11]; double s = 0.0;
    for (int i = 0; i < 11; ++i) { const double c = i - 5.0; vv[i] = exp(-(c * c) / 4.5); s += vv[i]; }
    for (int i = 0; i < 11; ++i) gw.g[i] = (float)(vv[i] / s);
  }

  hipMemsetAsync(acc, 0, 16384, stream);

  const int co[7] = {64, 64, 128, 128, 256, 256, 256};
  const int ci[7] = {3, 64, 64, 128, 128, 256, 256};
  WTArgs wa;
  size_t wtOff[7];
  {
    int e = 0;
    for (int i = 1; i < 7; ++i) {
      wa.w[i - 1] = W7[i]; wa.co[i - 1] = co[i]; wa.ci[i - 1] = ci[i];
      wa.cum[i - 1] = e; wtOff[i] = (size_t)e; e += co[i] * 9 * ci[i];
    }
    wa.cum[6] = e;
  }
  wt_transform_all<<<(wa.cum[6] + 255) / 256, 256, 0, stream>>>(wa, WT);

  auto zb = [&](unsigned short* buf, int HW, int C) {
    const int tot = 2 * (HW + 2) * C + 2 * HW * C;
    zero_border<<<(tot + 255) / 256, 256, 0, stream>>>(buf, HW, HW, C);
  };
  zb(C1, 224, 64); zb(Pl1, 112, 64); zb(C3, 112, 128);
  zb(Pl2, 56, 128); zb(C5, 56, 256); zb(C6, 56, 256);

  basic_stats<<<256, 256, 0, stream>>>(yt, yp, acc);
  exposure_k<<<392, 256, 0, stream>>>(yp, acc);
  pool4_lum_k<<<25, 256, 0, stream>>>(yt, yp, op, ep);
  spat_k<<<25, 256, 0, stream>>>(op, ep, acc);

  const int dims[5] = {224, 112, 56, 28, 14};
  const int pyrOff[4] = {0, 75264, 94080, 98784};
  const float* Xs = yt; const float* Ys = yp;
  for (int s = 0; s < 5; ++s) {
    const int n = dims[s], m = n - 10;
    const int totV = 6 * m * n;
    gaussV_k<<<(totV + 255) / 256, 256, 0, stream>>>(Xs, Ys, tmp5, n, gw);
    dim3 gh((m * m + 255) / 256, 6);
    gaussH_ssim_k<<<gh, 256, 0, stream>>>(tmp5, acc, n, s, gw);
    if (s < 4) {
      const int hn = n >> 1;
      const int totD = 6 * hn * hn;
      float* nx = pyrX + pyrOff[s];
      float* ny = pyrY + pyrOff[s];
      down2_k<<<(totD + 255) / 256, 256, 0, stream>>>(Xs, nx, n);
      down2_k<<<(totD + 255) / 256, 256, 0, stream>>>(Ys, ny, n);
      Xs = nx; Ys = ny;
    }
  }

  // VGG19[:16] on 4 images. conv_mfma<CIN, TY>: block tile 64co x 64px x TY rows.
  for (int b = 0; b < 2; ++b) {
    for (int pass = 0; pass < 2; ++pass) {
      const float* src = (pass == 0 ? yt : yp) + (size_t)b * 3 * 224 * 224;
      conv1_k<<<dim3(28, 28, 4), dim3(8, 8, 4), 0, stream>>>(src, W7[0], B7[0], C1, 224);
      conv_mfma<64, 2><<<dim3(4, 112, 1), 256, 0, stream>>>(C1, WT + wtOff[1], B7[1], T0, 224, 64);
      pool_nhwc<<<(112 * 112 * 64 + 255) / 256, 256, 0, stream>>>(T0, Pl1, 112, 112, 64);
      conv_mfma<64, 1><<<dim3(2, 112, 2), 256, 0, stream>>>(Pl1, WT + wtOff[2], B7[2], C3, 112, 128);
      conv_mfma<128, 1><<<dim3(2, 112, 2), 256, 0, stream>>>(C3, WT + wtOff[3], B7[3], T0, 112, 128);
      pool_nhwc<<<(56 * 56 * 128 + 255) / 256, 256, 0, stream>>>(T0, Pl2, 56, 56, 128);
      conv_mfma<128, 1><<<dim3(1, 56, 4), 256, 0, stream>>>(Pl2, WT + wtOff[4], B7[4], C5, 56, 256);
      conv_mfma<256, 1><<<dim3(1, 56, 4), 256, 0, stream>>>(C5, WT + wtOff[5], B7[5], C6, 56, 256);
      unsigned short* dst = (pass == 0) ? F : T0;
      conv_mfma<256, 1><<<dim3(1, 56, 4), 256, 0, stream>>>(C6, WT + wtOff[6], B7[6], dst, 56, 256);
    }
    perc_k<<<128, 256, 0, stream>>>(F, T0, acc);
  }

  final_k<<<1, 64, 0, stream>>>(acc, (float*)d_out);
}

// Round 6
// 421.339 us; speedup vs baseline: 8.3447x; 1.4663x over previous
//
#include <hip/hip_runtime.h>
#include <cmath>

typedef __attribute__((ext_vector_type(8))) short  short8;
typedef __attribute__((ext_vector_type(4))) float  floatx4;
typedef __attribute__((ext_vector_type(8))) unsigned short ushort8;

// Accumulator slots spread 64B apart to avoid same-cacheline atomic serialization.
#define SLOT(i) ((i) * 16)
#define ACC_L1   0
#define ACC_MSE  1
#define ACC_ST0  2
#define ACC_ST1  3
#define ACC_SP0  4
#define ACC_SP1  5
#define ACC_HV   6
#define ACC_WV   7
#define ACC_EXP  8
#define ACC_SPAT 9
#define ACC_PERC 10
#define SSIM_SLOT(scale, cs, img) (256 + ((scale) * 12 + (cs) * 6 + (img)) * 16)

struct GW { float g[11]; };

__device__ __forceinline__ float waveSum(float v) {
#pragma unroll
  for (int o = 32; o > 0; o >>= 1) v += __shfl_down(v, o, 64);
  return v;
}

__device__ __forceinline__ float blockSum256(float v) {
  __shared__ float red[4];
  const int tid = threadIdx.x;
  v = waveSum(v);
  __syncthreads();
  if ((tid & 63) == 0) red[tid >> 6] = v;
  __syncthreads();
  return red[0] + red[1] + red[2] + red[3];
}

__device__ __forceinline__ unsigned short f2bf(float f) {
  union { float f; unsigned int u; } v; v.f = f;
  const unsigned int u = v.u;
  return (unsigned short)((u + 0x7fffu + ((u >> 16) & 1u)) >> 16);
}
__device__ __forceinline__ float bf2f(unsigned short h) {
  union { unsigned int u; float f; } v; v.u = ((unsigned int)h) << 16;
  return v.f;
}

// ---------------- small loss terms ----------------

__global__ __launch_bounds__(256) void basic_stats(const float* __restrict__ yt,
                                                   const float* __restrict__ yp,
                                                   float* __restrict__ acc) {
  const int N = 2 * 3 * 224 * 224;
  float l1 = 0.f, mse = 0.f, st0 = 0.f, st1 = 0.f, sp0 = 0.f, sp1 = 0.f, hv = 0.f, wv = 0.f;
  for (int idx = blockIdx.x * 256 + threadIdx.x; idx < N; idx += 256 * 256) {
    const float t = yt[idx], p = yp[idx];
    const float d = p - t;
    const float ad = fabsf(d);
    l1 += (ad < 1.f) ? 0.5f * d * d : ad - 0.5f;
    mse += d * d;
    if (idx < 3 * 224 * 224) { st0 += t; sp0 += p; } else { st1 += t; sp1 += p; }
    const int w = idx % 224;
    const int h = (idx / 224) % 224;
    if (h < 223) { const float dv = yp[idx + 224] - p; hv += dv * dv; }
    if (w < 223) { const float dw = yp[idx + 1] - p; wv += dw * dw; }
  }
  float s;
  s = blockSum256(l1);  if (threadIdx.x == 0) atomicAdd(acc + SLOT(ACC_L1), s);
  s = blockSum256(mse); if (threadIdx.x == 0) atomicAdd(acc + SLOT(ACC_MSE), s);
  s = blockSum256(st0); if (threadIdx.x == 0) atomicAdd(acc + SLOT(ACC_ST0), s);
  s = blockSum256(st1); if (threadIdx.x == 0) atomicAdd(acc + SLOT(ACC_ST1), s);
  s = blockSum256(sp0); if (threadIdx.x == 0) atomicAdd(acc + SLOT(ACC_SP0), s);
  s = blockSum256(sp1); if (threadIdx.x == 0) atomicAdd(acc + SLOT(ACC_SP1), s);
  s = blockSum256(hv);  if (threadIdx.x == 0) atomicAdd(acc + SLOT(ACC_HV), s);
  s = blockSum256(wv);  if (threadIdx.x == 0) atomicAdd(acc + SLOT(ACC_WV), s);
}

__global__ __launch_bounds__(256) void exposure_k(const float* __restrict__ yp,
                                                  float* __restrict__ acc) {
  const int blk = blockIdx.x;
  const int b = blk / 196;
  const int rem = blk - b * 196;
  const int py = rem / 14, px = rem - py * 14;
  float s = 0.f;
  for (int e = threadIdx.x; e < 768; e += 256) {
    const int c = e >> 8;
    const int rr = (e >> 4) & 15;
    const int cc = e & 15;
    s += yp[(((size_t)b * 3 + c) * 224 + py * 16 + rr) * 224 + px * 16 + cc];
  }
  const float t = blockSum256(s);
  if (threadIdx.x == 0) {
    const float m = t * (1.f / 768.f) - 0.6f;
    atomicAdd(acc + SLOT(ACC_EXP), m * m);
  }
}

__global__ __launch_bounds__(256) void pool4_lum_k(const float* __restrict__ yt,
                                                   const float* __restrict__ yp,
                                                   float* __restrict__ op,
                                                   float* __restrict__ ep) {
  const int idx = blockIdx.x * 256 + threadIdx.x;
  if (idx >= 2 * 56 * 56) return;
  const int b = idx / 3136;
  const int rem = idx - b * 3136;
  const int r = rem / 56, cl = rem - r * 56;
  float so = 0.f, se = 0.f;
  for (int c = 0; c < 3; ++c)
    for (int dy = 0; dy < 4; ++dy)
      for (int dx = 0; dx < 4; ++dx) {
        const size_t off = (((size_t)b * 3 + c) * 224 + (r * 4 + dy)) * 224 + cl * 4 + dx;
        so += yt[off]; se += yp[off];
      }
  op[idx] = so * (1.f / 48.f);
  ep[idx] = se * (1.f / 48.f);
}

__global__ __launch_bounds__(256) void spat_k(const float* __restrict__ op,
                                              const float* __restrict__ ep,
                                              float* __restrict__ acc) {
  const int idx = blockIdx.x * 256 + threadIdx.x;
  float v = 0.f;
  if (idx < 6272) {
    const int rem = idx % 3136;
    const int r = rem / 56, cl = rem - r * 56;
    const float oc = op[idx], ec = ep[idx];
    const float ol = (cl > 0)  ? op[idx - 1]  : 0.f;
    const float el = (cl > 0)  ? ep[idx - 1]  : 0.f;
    const float orr = (cl < 55) ? op[idx + 1]  : 0.f;
    const float er  = (cl < 55) ? ep[idx + 1]  : 0.f;
    const float ou = (r > 0)   ? op[idx - 56] : 0.f;
    const float eu = (r > 0)   ? ep[idx - 56] : 0.f;
    const float od = (r < 55)  ? op[idx + 56] : 0.f;
    const float ed = (r < 55)  ? ep[idx + 56] : 0.f;
    float d;
    d = (oc - ol) - (ec - el);   v += d * d;
    d = (oc - orr) - (ec - er);  v += d * d;
    d = (oc - ou) - (ec - eu);   v += d * d;
    d = (oc - od) - (ec - ed);   v += d * d;
  }
  const float t = blockSum256(v);
  if (threadIdx.x == 0) atomicAdd(acc + SLOT(ACC_SPAT), t);
}

// ---------------- MS-SSIM ----------------

__global__ __launch_bounds__(256) void gaussV_k(const float* __restrict__ X,
                                                const float* __restrict__ Y,
                                                float* __restrict__ tmp, int n, GW gw) {
  const int m = n - 10;
  const int total = 6 * m * n;
  const int idx = blockIdx.x * 256 + threadIdx.x;
  if (idx >= total) return;
  const int img = idx / (m * n);
  const int rem = idx - img * (m * n);
  const int r = rem / n, cl = rem - r * n;
  const float* xb = X + (size_t)img * n * n + (size_t)r * n + cl;
  const float* yb = Y + (size_t)img * n * n + (size_t)r * n + cl;
  float sx = 0.f, sy = 0.f, sxx = 0.f, syy = 0.f, sxy = 0.f;
#pragma unroll
  for (int t = 0; t < 11; ++t) {
    const float xv = xb[(size_t)t * n];
    const float yv = yb[(size_t)t * n];
    const float g = gw.g[t];
    sx += g * xv; sy += g * yv;
    sxx += g * xv * xv; syy += g * yv * yv; sxy += g * xv * yv;
  }
  const size_t st = (size_t)6 * m * n;
  tmp[idx] = sx; tmp[st + idx] = sy;
  tmp[2 * st + idx] = sxx; tmp[3 * st + idx] = syy; tmp[4 * st + idx] = sxy;
}

__global__ __launch_bounds__(256) void gaussH_ssim_k(const float* __restrict__ tmp,
                                                     float* __restrict__ acc,
                                                     int n, int scale, GW gw) {
  const int m = n - 10;
  const int img = blockIdx.y;
  const int pid = blockIdx.x * 256 + threadIdx.x;
  float sv = 0.f, cv = 0.f;
  if (pid < m * m) {
    const int r = pid / m, cl = pid - r * m;
    const size_t st = (size_t)6 * m * n;
    const float* t0 = tmp + (size_t)img * m * n + (size_t)r * n + cl;
    float mu1 = 0.f, mu2 = 0.f, e11 = 0.f, e22 = 0.f, e12 = 0.f;
#pragma unroll
    for (int t = 0; t < 11; ++t) {
      const float g = gw.g[t];
      mu1 += g * t0[t];
      mu2 += g * t0[st + t];
      e11 += g * t0[2 * st + t];
      e22 += g * t0[3 * st + t];
      e12 += g * t0[4 * st + t];
    }
    const float C1 = 1e-4f, C2 = 9e-4f;
    const float s11 = e11 - mu1 * mu1;
    const float s22 = e22 - mu2 * mu2;
    const float s12 = e12 - mu1 * mu2;
    cv = (2.f * s12 + C2) / (s11 + s22 + C2);
    sv = ((2.f * mu1 * mu2 + C1) / (mu1 * mu1 + mu2 * mu2 + C1)) * cv;
  }
  float t = blockSum256(sv);
  if (threadIdx.x == 0) atomicAdd(acc + SSIM_SLOT(scale, 0, img), t);
  t = blockSum256(cv);
  if (threadIdx.x == 0) atomicAdd(acc + SSIM_SLOT(scale, 1, img), t);
}

// 2x2 avg pool of X AND Y in one launch: 12 maps
__global__ __launch_bounds__(256) void down2_k(const float* __restrict__ X,
                                               const float* __restrict__ Y,
                                               float* __restrict__ OX,
                                               float* __restrict__ OY, int n) {
  const int h = n >> 1;
  const int total = 12 * h * h;
  const int idx = blockIdx.x * 256 + threadIdx.x;
  if (idx >= total) return;
  int j = idx / (h * h);
  const int rem = idx - j * (h * h);
  const float* src; float* dst;
  if (j < 6) { src = X; dst = OX; } else { src = Y; dst = OY; j -= 6; }
  const int r = rem / h, cl = rem - r * h;
  const float* xb = src + (size_t)j * n * n + (size_t)(2 * r) * n + 2 * cl;
  dst[(size_t)j * h * h + rem] = 0.25f * (xb[0] + xb[1] + xb[n] + xb[n + 1]);
}

// ---------------- VGG ----------------

struct WTArgs {
  const float* w[6];
  int co[6], ci[6];
  int cum[7];
};
__global__ __launch_bounds__(256) void wt_transform_all(WTArgs a, unsigned short* __restrict__ dst) {
  const int idx = blockIdx.x * 256 + threadIdx.x;
  if (idx >= a.cum[6]) return;
  int L = 0;
  while (idx >= a.cum[L + 1]) ++L;
  const int r = idx - a.cum[L];
  const int Cin = a.ci[L];
  const int cin = r % Cin;
  const int t = r / Cin;
  const int tap = t % 9;
  const int cout = t / 9;
  dst[idx] = f2bf(a.w[L][((size_t)cout * Cin + cin) * 9 + tap]);
}

// zero 1-px border of 4 batched padded NHWC buffers [4][H+2][W+2][C]
__global__ __launch_bounds__(256) void zero_border(unsigned short* __restrict__ buf,
                                                   int H, int W, int C) {
  const int Wp = W + 2;
  const int rowE = Wp * C;
  const int per = 2 * rowE + 2 * H * C;
  const int idx = blockIdx.x * 256 + threadIdx.x;
  if (idx >= 4 * per) return;
  const int img = idx / per;
  const int k0 = idx - img * per;
  size_t o;
  if (k0 < rowE) o = k0;
  else if (k0 < 2 * rowE) o = (size_t)(H + 1) * rowE + (k0 - rowE);
  else {
    const int k = k0 - 2 * rowE;
    const int y = k / (2 * C) + 1;
    const int r = k % (2 * C);
    const int x = (r < C) ? 0 : (W + 1);
    const int c = (r < C) ? r : (r - C);
    o = (size_t)y * rowE + (size_t)x * C + c;
  }
  buf[(size_t)img * (H + 2) * rowE + o] = 0;
}

// layer1 batched: Cin=3 direct conv, 4 images. grid (28,28,16): z = img*4+quarter
__global__ __launch_bounds__(256) void conv1_k(
    const float* __restrict__ yt, const float* __restrict__ yp,
    const float* __restrict__ wt, const float* __restrict__ bias,
    unsigned short* __restrict__ out) {
  __shared__ float sIn[3][10][12];
  const int tx = threadIdx.x, ty = threadIdx.y, tz = threadIdx.z;
  const int tid = (tz << 6) | (ty << 3) | tx;
  const int img = blockIdx.z >> 2;            // p*2+b: 0,1=true; 2,3=pred
  const int zq = blockIdx.z & 3;
  const float* in = ((img >> 1) ? yp : yt) + (size_t)(img & 1) * 3 * 224 * 224;
  const int x0 = blockIdx.x << 3, y0 = blockIdx.y << 3;
  const int x = x0 + tx, y = y0 + ty;
  int wrow = (zq * 16 + tz * 4) * 27;
  wrow = __builtin_amdgcn_readfirstlane(wrow);

  for (int el = tid; el < 300; el += 256) {
    const int ci = el / 100;
    const int rem = el - ci * 100;
    const int r = rem / 10, cl = rem - r * 10;
    const int gy = y0 - 1 + r, gx = x0 - 1 + cl;
    float v = 0.f;
    if (gy >= 0 && gy < 224 && gx >= 0 && gx < 224)
      v = in[((size_t)ci * 224 + gy) * 224 + gx];
    sIn[ci][r][cl] = v;
  }
  __syncthreads();

  float a0 = 0.f, a1 = 0.f, a2 = 0.f, a3 = 0.f;
#pragma unroll
  for (int ci = 0; ci < 3; ++ci) {
    float xv[9];
#pragma unroll
    for (int ky = 0; ky < 3; ++ky)
#pragma unroll
      for (int kx = 0; kx < 3; ++kx)
        xv[ky * 3 + kx] = sIn[ci][ty + ky][tx + kx];
    const float* wp = wt + wrow + ci * 9;
#pragma unroll
    for (int k = 0; k < 9; ++k) {
      a0 = fmaf(xv[k], wp[k], a0);
      a1 = fmaf(xv[k], wp[27 + k], a1);
      a2 = fmaf(xv[k], wp[54 + k], a2);
      a3 = fmaf(xv[k], wp[81 + k], a3);
    }
  }
  const int coB = zq * 16 + tz * 4;
  const size_t o = (size_t)img * 226 * 226 * 64 + ((size_t)(y + 1) * 226 + (x + 1)) * 64 + coB;
  uint2 pk;
  pk.x = (unsigned int)f2bf(fmaxf(a0 + bias[coB + 0], 0.f)) |
         ((unsigned int)f2bf(fmaxf(a1 + bias[coB + 1], 0.f)) << 16);
  pk.y = (unsigned int)f2bf(fmaxf(a2 + bias[coB + 2], 0.f)) |
         ((unsigned int)f2bf(fmaxf(a3 + bias[coB + 3], 0.f)) << 16);
  *(uint2*)(out + o) = pk;
}

// implicit-GEMM conv3x3, batched (4 images), m97-style barrier-anchored LDS staging.
// Block tile: 64co x 64px x 2 rows. Waves: wc=co-half, wr=row. Wave tile: 32co x 64px x 1row
// -> per tap: 2 af + 4 bfr ds_read_b128 : 8 MFMA (0.75 reads/MFMA).
// grid: x = px-tiles, y = img*rowsPI + row-tile, z = cout/64. rowsPI = H/2.
// LDS strides 296/40 elem: dword-stride ≡ 4·odd (mod 32) -> b128 reads conflict-free.
template<int CIN>
__global__ __launch_bounds__(256, 2) void conv_mfma(
    const unsigned short* __restrict__ in, const unsigned short* __restrict__ wtp,
    const float* __restrict__ bias, unsigned short* __restrict__ out,
    int W, int Cout, int rowsPI) {
  constexpr int NSLAB = CIN / 32;
  constexpr int AST = 296;
  constexpr int BST = 40;
  constexpr int NBRUN = 4 * 66;            // (TY=2 + 2 halo) rows x 66 px
  constexpr int NBCH = NBRUN * 4;
  __shared__ unsigned short As[64 * AST];
  __shared__ unsigned short Bs[NBRUN * BST];

  const int tid = threadIdx.x;
  const int lane = tid & 63;
  const int wave = tid >> 6;
  const int quad = lane >> 4;
  const int lr = lane & 15;
  const int wc = wave & 1;                 // co half
  const int wr = wave >> 1;                // output row within tile
  const int img = blockIdx.y / rowsPI;
  const int y0 = (blockIdx.y - img * rowsPI) * 2;
  const int x0 = blockIdx.x * 64;
  const int cob = blockIdx.z * 64;
  const int Wp = W + 2;
  const int H = rowsPI * 2;
  const unsigned short* inI = in + (size_t)img * (H + 2) * Wp * CIN;
  unsigned short* outI = out + (size_t)img * (H + 2) * Wp * Cout;

  floatx4 acc[2][4];
#pragma unroll
  for (int m = 0; m < 2; ++m)
#pragma unroll
    for (int n = 0; n < 4; ++n) acc[m][n] = (floatx4){0.f, 0.f, 0.f, 0.f};

  const int abase = (wc * 32 + lr) * AST + quad * 8;
  const int bq = quad * 8;

  for (int s = 0; s < NSLAB; ++s) {
    __syncthreads();
    // stage A: 64co x 9tap x 32ci = 2304 16B chunks (9/thread)
#pragma unroll
    for (int i = 0; i < 9; ++i) {
      const int ee = tid + i * 256;
      const int cout = ee / 36;
      const int rem = ee - cout * 36;
      const int tap = rem >> 2;
      const int part = rem & 3;
      const short8 v = *(const short8*)(wtp + ((size_t)(cob + cout) * 9 + tap) * CIN + s * 32 + part * 8);
      *(short8*)(As + cout * AST + tap * 32 + part * 8) = v;
    }
    // stage B patch: 4 rows x 66 px x 32 ci
#pragma unroll
    for (int i = 0; i < (NBCH + 255) / 256; ++i) {
      const int ee = tid + i * 256;
      if (ee < NBCH) {
        const int part = ee & 3;
        const int run = ee >> 2;
        const int row = run / 66;
        const int px = run - row * 66;
        short8 v = {0, 0, 0, 0, 0, 0, 0, 0};
        const int gx = x0 + px;
        if (gx < Wp)
          v = *(const short8*)(inI + ((size_t)(y0 + row) * Wp + gx) * CIN + s * 32 + part * 8);
        *(short8*)(Bs + run * BST + part * 8) = v;
      }
    }
    __syncthreads();

#pragma unroll
    for (int dy = 0; dy < 3; ++dy)
#pragma unroll
      for (int dx = 0; dx < 3; ++dx) {
        const int tap = dy * 3 + dx;
        const short8 af0 = *(const short8*)(As + abase + tap * 32);
        const short8 af1 = *(const short8*)(As + abase + 16 * AST + tap * 32);
        short8 bfr[4];
#pragma unroll
        for (int n = 0; n < 4; ++n)
          bfr[n] = *(const short8*)(Bs + ((wr + dy) * 66 + n * 16 + lr + dx) * BST + bq);
#pragma unroll
        for (int n = 0; n < 4; ++n) {
          acc[0][n] = __builtin_amdgcn_mfma_f32_16x16x32_bf16(af0, bfr[n], acc[0][n], 0, 0, 0);
          acc[1][n] = __builtin_amdgcn_mfma_f32_16x16x32_bf16(af1, bfr[n], acc[1][n], 0, 0, 0);
        }
      }
  }

#pragma unroll
  for (int m = 0; m < 2; ++m) {
    const int cb = cob + wc * 32 + m * 16 + quad * 4;
#pragma unroll
    for (int n = 0; n < 4; ++n) {
      const int px = x0 + n * 16 + lr;
      if (px < W) {
        const float v0 = fmaxf(acc[m][n].x + bias[cb + 0], 0.f);
        const float v1 = fmaxf(acc[m][n].y + bias[cb + 1], 0.f);
        const float v2 = fmaxf(acc[m][n].z + bias[cb + 2], 0.f);
        const float v3 = fmaxf(acc[m][n].w + bias[cb + 3], 0.f);
        uint2 pk;
        pk.x = (unsigned int)f2bf(v0) | ((unsigned int)f2bf(v1) << 16);
        pk.y = (unsigned int)f2bf(v2) | ((unsigned int)f2bf(v3) << 16);
        *(uint2*)(outI + ((size_t)(y0 + wr + 1) * Wp + px + 1) * Cout + cb) = pk;
      }
    }
  }
}

// batched 2x2 maxpool on padded NHWC bf16
__global__ __launch_bounds__(256) void pool_nhwc(const unsigned short* __restrict__ in,
                                                 unsigned short* __restrict__ out,
                                                 int Ho, int Wo, int C) {
  const int per = Ho * Wo * C;
  const int idx = blockIdx.x * 256 + threadIdx.x;
  if (idx >= 4 * per) return;
  const int img = idx / per;
  const int k = idx - img * per;
  const int c = k % C;
  const int p = k / C;
  const int x = p % Wo, y = p / Wo;
  const int Wi = 2 * Wo + 2;
  const unsigned short* ib = in + (size_t)img * (2 * Ho + 2) * Wi * C +
                             ((size_t)(2 * y + 1) * Wi + (2 * x + 1)) * C + c;
  const float a = bf2f(ib[0]), b = bf2f(ib[C]);
  const float d = bf2f(ib[(size_t)Wi * C]), e = bf2f(ib[(size_t)Wi * C + C]);
  out[(size_t)img * (Ho + 2) * (Wo + 2) * C + ((size_t)(y + 1) * (Wo + 2) + x + 1) * C + c] =
      f2bf(fmaxf(fmaxf(a, b), fmaxf(d, e)));
}

// perceptual over both batch pairs: F[img][58][58][256], pairs (0,2),(1,3)
__global__ __launch_bounds__(256) void perc_k(const unsigned short* __restrict__ f,
                                              float* __restrict__ acc) {
  const int PER = 56 * 56 * 256 / 8;       // 100352 chunks per image
  const size_t STR = (size_t)58 * 58 * 256;
  float v = 0.f;
  for (int ch = blockIdx.x * 256 + threadIdx.x; ch < 2 * PER; ch += 256 * 256) {
    const int q = ch / PER;
    const int r = ch - q * PER;
    const int e = r * 8;
    const int c = e & 255;
    const int p = e >> 8;
    const int x = p % 56, y = p / 56;
    const size_t o = ((size_t)(y + 1) * 58 + x + 1) * 256 + c;
    const ushort8 a = *(const ushort8*)(f + q * STR + o);
    const ushort8 b = *(const ushort8*)(f + (q + 2) * STR + o);
#pragma unroll
    for (int j = 0; j < 8; ++j) {
      const float d = bf2f(a[j]) - bf2f(b[j]);
      v = fmaf(d, d, v);
    }
  }
  const float t = blockSum256(v);
  if (threadIdx.x == 0) atomicAdd(acc + SLOT(ACC_PERC), t);
}

// ---------------- final combine ----------------
__global__ void final_k(const float* __restrict__ acc, float* __restrict__ out) {
  if (threadIdx.x != 0 || blockIdx.x != 0) return;
  const float NPIX = 2.f * 3.f * 224.f * 224.f;
  const float l1 = acc[SLOT(ACC_L1)] / NPIX;
  const float mse = acc[SLOT(ACC_MSE)] / NPIX;
  const float psnr = 40.f + 10.f * log10f(mse);
  const float cm = 1.f / (3.f * 224.f * 224.f);
  const float color = 0.5f * (fabsf(acc[SLOT(ACC_ST0)] - acc[SLOT(ACC_SP0)]) +
                              fabsf(acc[SLOT(ACC_ST1)] - acc[SLOT(ACC_SP1)])) * cm;
  const float ill = acc[SLOT(ACC_HV)] / 669.f + acc[SLOT(ACC_WV)] / 448.f;
  const float expl = acc[SLOT(ACC_EXP)] / 392.f;
  const float spat = acc[SLOT(ACC_SPAT)] / 6272.f;
  const float perc = acc[SLOT(ACC_PERC)] / 1605632.f;
  const float wms[5] = {0.0448f, 0.2856f, 0.3001f, 0.2363f, 0.1333f};
  const int ns[5] = {214, 102, 46, 18, 4};
  float msum = 0.f;
  for (int img = 0; img < 6; ++img) {
    float prod = 1.f;
    for (int s = 0; s < 5; ++s) {
      const float denom = (float)(ns[s] * ns[s]);
      float v = (s == 4) ? acc[SSIM_SLOT(s, 0, img)] / denom
                         : acc[SSIM_SLOT(s, 1, img)] / denom;
      v = fmaxf(v, 0.f);
      prod *= powf(v, wms[s]);
    }
    msum += prod;
  }
  const float msssim = msum / 6.f;
  out[0] = l1 + 0.06f * perc + 0.0083f * psnr + 0.25f * color +
           0.5f * (1.f - msssim) + 0.1f * expl + 0.1f * ill + 0.1f * spat;
}

extern "C" void kernel_launch(void* const* d_in, const int* in_sizes, int n_in,
                              void* d_out, int out_size, void* d_ws, size_t ws_size,
                              hipStream_t stream) {
  const float* yt = (const float*)d_in[0];
  const float* yp = (const float*)d_in[1];
  const float* W7[7]; const float* B7[7];
  for (int i = 0; i < 7; ++i) {
    W7[i] = (const float*)d_in[2 + 2 * i];
    B7[i] = (const float*)d_in[3 + 2 * i];
  }

  // Batched buffers: [4 images][H+2][W+2][C]. ~100 MB total (ws is ~268 MB).
  char* ws = (char*)d_ws;
  float* acc = (float*)ws;
  size_t off = 16384;
  float* op = (float*)(ws + off); off += 2 * 3136 * 4;
  float* ep = (float*)(ws + off); off += 2 * 3136 * 4;
  auto align256 = [&]() { off = (off + 255) & ~(size_t)255; };
  align256(); unsigned short* C1  = (unsigned short*)(ws + off); off += (size_t)4 * 226 * 226 * 64 * 2;
  align256(); unsigned short* T0  = (unsigned short*)(ws + off); off += (size_t)4 * 226 * 226 * 64 * 2;
  align256(); unsigned short* Pl1 = (unsigned short*)(ws + off); off += (size_t)4 * 114 * 114 * 64 * 2;
  align256(); unsigned short* C3  = (unsigned short*)(ws + off); off += (size_t)4 * 114 * 114 * 128 * 2;
  align256(); unsigned short* Pl2 = (unsigned short*)(ws + off); off += (size_t)4 * 58 * 58 * 128 * 2;
  align256(); unsigned short* C5  = (unsigned short*)(ws + off); off += (size_t)4 * 58 * 58 * 256 * 2;
  align256(); unsigned short* C6  = (unsigned short*)(ws + off); off += (size_t)4 * 58 * 58 * 256 * 2;
  align256(); unsigned short* F   = (unsigned short*)(ws + off); off += (size_t)4 * 58 * 58 * 256 * 2;
  align256(); unsigned short* WT  = (unsigned short*)(ws + off); off += (size_t)1732608 * 2;
  if (ws_size < off) return;

  float* tmp5 = (float*)T0;          // pre-VGG scratch (5.76 MB needed)
  float* pyrX = (float*)F;
  float* pyrY = (float*)F + 100000;

  GW gw;
  {
    double vv[11]; double s = 0.0;
    for (int i = 0; i < 11; ++i) { const double c = i - 5.0; vv[i] = exp(-(c * c) / 4.5); s += vv[i]; }
    for (int i = 0; i < 11; ++i) gw.g[i] = (float)(vv[i] / s);
  }

  hipMemsetAsync(acc, 0, 16384, stream);

  const int co[7] = {64, 64, 128, 128, 256, 256, 256};
  const int ci[7] = {3, 64, 64, 128, 128, 256, 256};
  WTArgs wa;
  size_t wtOff[7];
  {
    int e = 0;
    for (int i = 1; i < 7; ++i) {
      wa.w[i - 1] = W7[i]; wa.co[i - 1] = co[i]; wa.ci[i - 1] = ci[i];
      wa.cum[i - 1] = e; wtOff[i] = (size_t)e; e += co[i] * 9 * ci[i];
    }
    wa.cum[6] = e;
  }
  wt_transform_all<<<(wa.cum[6] + 255) / 256, 256, 0, stream>>>(wa, WT);

  auto zb = [&](unsigned short* buf, int HW, int C) {
    const int tot = 4 * (2 * (HW + 2) * C + 2 * HW * C);
    zero_border<<<(tot + 255) / 256, 256, 0, stream>>>(buf, HW, HW, C);
  };
  zb(C1, 224, 64); zb(Pl1, 112, 64); zb(C3, 112, 128);
  zb(Pl2, 56, 128); zb(C5, 56, 256); zb(C6, 56, 256);

  basic_stats<<<256, 256, 0, stream>>>(yt, yp, acc);
  exposure_k<<<392, 256, 0, stream>>>(yp, acc);
  pool4_lum_k<<<25, 256, 0, stream>>>(yt, yp, op, ep);
  spat_k<<<25, 256, 0, stream>>>(op, ep, acc);

  const int dims[5] = {224, 112, 56, 28, 14};
  const int pyrOff[4] = {0, 75264, 94080, 98784};
  const float* Xs = yt; const float* Ys = yp;
  for (int s = 0; s < 5; ++s) {
    const int n = dims[s], m = n - 10;
    const int totV = 6 * m * n;
    gaussV_k<<<(totV + 255) / 256, 256, 0, stream>>>(Xs, Ys, tmp5, n, gw);
    dim3 gh((m * m + 255) / 256, 6);
    gaussH_ssim_k<<<gh, 256, 0, stream>>>(tmp5, acc, n, s, gw);
    if (s < 4) {
      const int hn = n >> 1;
      float* nx = pyrX + pyrOff[s];
      float* ny = pyrY + pyrOff[s];
      down2_k<<<(12 * hn * hn + 255) / 256, 256, 0, stream>>>(Xs, Ys, nx, ny, n);
      Xs = nx; Ys = ny;
    }
  }

  // VGG19[:16], all 4 images per dispatch
  conv1_k<<<dim3(28, 28, 16), dim3(8, 8, 4), 0, stream>>>(yt, yp, W7[0], B7[0], C1);
  conv_mfma<64> <<<dim3(4, 4 * 112, 1), 256, 0, stream>>>(C1,  WT + wtOff[1], B7[1], T0, 224, 64, 112);
  pool_nhwc<<<(4 * 112 * 112 * 64 + 255) / 256, 256, 0, stream>>>(T0, Pl1, 112, 112, 64);
  conv_mfma<64> <<<dim3(2, 4 * 56, 2), 256, 0, stream>>>(Pl1, WT + wtOff[2], B7[2], C3, 112, 128, 56);
  conv_mfma<128><<<dim3(2, 4 * 56, 2), 256, 0, stream>>>(C3,  WT + wtOff[3], B7[3], T0, 112, 128, 56);
  pool_nhwc<<<(4 * 56 * 56 * 128 + 255) / 256, 256, 0, stream>>>(T0, Pl2, 56, 56, 128);
  conv_mfma<128><<<dim3(1, 4 * 28, 4), 256, 0, stream>>>(Pl2, WT + wtOff[4], B7[4], C5, 56, 256, 28);
  conv_mfma<256><<<dim3(1, 4 * 28, 4), 256, 0, stream>>>(C5,  WT + wtOff[5], B7[5], C6, 56, 256, 28);
  conv_mfma<256><<<dim3(1, 4 * 28, 4), 256, 0, stream>>>(C6,  WT + wtOff[6], B7[6], F,  56, 256, 28);
  perc_k<<<256, 256, 0, stream>>>(F, acc);

  final_k<<<1, 64, 0, stream>>>(acc, (float*)d_out);
}